// Round 1
// baseline (246.571 us; speedup 1.0000x reference)
//
#include <hip/hip_runtime.h>
#include <hip/hip_bf16.h>

#define B_ 2
#define H_ 8
#define L_ 4096
#define D_ 64
#define NB_ 64
#define TOPK_ 16
#define BH_ 16

typedef __bf16 bf16x8 __attribute__((ext_vector_type(8)));
typedef float f32x4 __attribute__((ext_vector_type(4)));

// ---------------------------------------------------------------------------
// Kernel 1: per-block means of q and k.  grid = BH_*NB_ blocks, 256 threads.
// pq[bh*NB_*D_ + m*D_ + d], pk likewise (pk is UNcentered block mean).
// ---------------------------------------------------------------------------
__global__ __launch_bounds__(256) void block_means_kernel(
    const float* __restrict__ q, const float* __restrict__ k,
    float* __restrict__ pq, float* __restrict__ pk) {
  const int blk = blockIdx.x;          // bh*64 + m
  const int bh = blk >> 6, m = blk & 63;
  const int d = threadIdx.x & 63, g = threadIdx.x >> 6;   // g in 0..3
  const float* qb = q + ((size_t)bh * L_ + m * 64 + g * 16) * D_ + d;
  const float* kb = k + ((size_t)bh * L_ + m * 64 + g * 16) * D_ + d;
  float sq = 0.f, sk = 0.f;
#pragma unroll
  for (int i = 0; i < 16; i++) { sq += qb[(size_t)i * D_]; sk += kb[(size_t)i * D_]; }
  __shared__ float bufq[4][64];
  __shared__ float bufk[4][64];
  bufq[g][d] = sq; bufk[g][d] = sk;
  __syncthreads();
  if (g == 0) {
    float tq = bufq[0][d] + bufq[1][d] + bufq[2][d] + bufq[3][d];
    float tk = bufk[0][d] + bufk[1][d] + bufk[2][d] + bufk[3][d];
    pq[(size_t)blk * 64 + d] = tq * (1.f / 64.f);
    pk[(size_t)blk * 64 + d] = tk * (1.f / 64.f);
  }
}

// ---------------------------------------------------------------------------
// Kernel 2: scores = pq . (pk - mean_m(pk)), top-16 per row.  grid = BH_,
// 256 threads (4 waves, each wave does 16 rows).  All fp32 (selection must
// match the numpy reference).
// ---------------------------------------------------------------------------
__global__ __launch_bounds__(256) void blockmap_kernel(
    const float* __restrict__ pq, const float* __restrict__ pk,
    int* __restrict__ lut) {
  const int bh = blockIdx.x;
  const int t = threadIdx.x;
  const int lane = t & 63;
  __shared__ float s_pq[64][65];   // +1 pad: bank-conflict-free row reads
  __shared__ float s_pk[64][65];
  __shared__ float s_km[64];
#pragma unroll
  for (int i = 0; i < 16; i++) {
    int idx = i * 256 + t;
    int r = idx >> 6, c = idx & 63;
    s_pq[r][c] = pq[(size_t)bh * 4096 + idx];
    s_pk[r][c] = pk[(size_t)bh * 4096 + idx];
  }
  __syncthreads();
  if (t < 64) {
    float s = 0.f;
#pragma unroll 8
    for (int r = 0; r < 64; r++) s += s_pk[r][t];
    s_km[t] = s * (1.f / 64.f);
  }
  __syncthreads();
  for (int i = 0; i < 16; i++) {
    const int row = (t >> 6) * 16 + i;
    float sc = 0.f;
#pragma unroll 8
    for (int d2 = 0; d2 < 64; ++d2)
      sc += s_pq[row][d2] * (s_pk[lane][d2] - s_km[d2]);
    // iterative argmax top-16 (total order on (value, -index) -> uniform result)
    float sval = sc;
    for (int it = 0; it < TOPK_; ++it) {
      float vv = sval; int ix = lane;
#pragma unroll
      for (int off = 32; off; off >>= 1) {
        float ov = __shfl_xor(vv, off, 64);
        int   oi = __shfl_xor(ix, off, 64);
        if (ov > vv || (ov == vv && oi < ix)) { vv = ov; ix = oi; }
      }
      if (lane == 0) lut[((size_t)bh * 64 + row) * TOPK_ + it] = ix;
      if (lane == ix) sval = -__builtin_inff();
    }
  }
}

// ---------------------------------------------------------------------------
// Kernel 3: sparse flash attention over the selected blocks.
// grid = BH_*NB_ (one block per (bh, q-block)), 256 threads = 4 waves.
// Wave w owns q rows [w*16, w*16+16), all 64 output dims.
// LDS: K (swizzled [key][d]), V transposed (swizzled [d][key]), per-wave P.
// Swizzle: 16B chunk index ^= (row & 7)  (G4 fix for 128B-stride rows).
// ---------------------------------------------------------------------------
__global__ __launch_bounds__(256) void sparse_attn_kernel(
    const float* __restrict__ q, const float* __restrict__ k,
    const float* __restrict__ v, const int* __restrict__ lut,
    float* __restrict__ out) {
  const int blk = blockIdx.x;
  const int bh = blk >> 6, m = blk & 63;
  const int tid = threadIdx.x;
  const int lane = tid & 63;
  const int w = tid >> 6;
  const int l16 = lane & 15, lhi = lane >> 4;

  __shared__ __align__(16) __bf16 Kl[64 * 64];
  __shared__ __align__(16) __bf16 Vt[64 * 64];
  __shared__ __align__(16) __bf16 Pl[4][16 * 64];

  const size_t base = (size_t)bh * L_ * D_;

  // Q A-fragments, qk_scale folded in (0.125 = 2^-3, exact in bf16 rounding)
  bf16x8 qf[2];
  {
    const float* qrow = q + base + (size_t)(m * 64 + w * 16 + l16) * D_;
#pragma unroll
    for (int s = 0; s < 2; s++) {
      const float* p0 = qrow + s * 32 + lhi * 8;
      float4 a = *(const float4*)p0;
      float4 b = *(const float4*)(p0 + 4);
      bf16x8 f;
      f[0] = (__bf16)(a.x * 0.125f); f[1] = (__bf16)(a.y * 0.125f);
      f[2] = (__bf16)(a.z * 0.125f); f[3] = (__bf16)(a.w * 0.125f);
      f[4] = (__bf16)(b.x * 0.125f); f[5] = (__bf16)(b.y * 0.125f);
      f[6] = (__bf16)(b.z * 0.125f); f[7] = (__bf16)(b.w * 0.125f);
      qf[s] = f;
    }
  }

  f32x4 acc_o[4];
#pragma unroll
  for (int i = 0; i < 4; i++) acc_o[i] = (f32x4){0.f, 0.f, 0.f, 0.f};
  float m_run[4] = {-__builtin_inff(), -__builtin_inff(), -__builtin_inff(), -__builtin_inff()};
  float l_run[4] = {0.f, 0.f, 0.f, 0.f};

  const int srow = tid >> 2;          // staging row (= key index), 0..63
  const int sc16 = (tid & 3) * 16;    // staging col base (d)

  for (int it = 0; it < TOPK_; ++it) {
    const int kb = lut[(size_t)blk * TOPK_ + it];
    __syncthreads();   // previous iter's LDS reads are complete (consumed by MFMA)
    {
      const float* ks = k + base + (size_t)(kb * 64 + srow) * D_ + sc16;
      const float* vs = v + base + (size_t)(kb * 64 + srow) * D_ + sc16;
      float kf[16], vf[16];
#pragma unroll
      for (int h = 0; h < 4; h++) {
        float4 t4 = *(const float4*)(ks + h * 4);
        kf[h * 4 + 0] = t4.x; kf[h * 4 + 1] = t4.y; kf[h * 4 + 2] = t4.z; kf[h * 4 + 3] = t4.w;
        float4 u4 = *(const float4*)(vs + h * 4);
        vf[h * 4 + 0] = u4.x; vf[h * 4 + 1] = u4.y; vf[h * 4 + 2] = u4.z; vf[h * 4 + 3] = u4.w;
      }
#pragma unroll
      for (int h = 0; h < 2; h++) {
        int c8 = (sc16 >> 3) + h;
        bf16x8 kw;
#pragma unroll
        for (int j = 0; j < 8; j++) kw[j] = (__bf16)kf[h * 8 + j];
        *(bf16x8*)&Kl[srow * 64 + ((c8 ^ (srow & 7)) << 3)] = kw;
      }
#pragma unroll
      for (int i = 0; i < 16; i++) {
        int d = sc16 + i;
        Vt[d * 64 + (srow ^ ((d & 7) << 3))] = (__bf16)vf[i];
      }
    }
    __syncthreads();

    // ---- S = Q @ K^T (4 key-tiles of 16) ----
    f32x4 accs[4];
#pragma unroll
    for (int i = 0; i < 4; i++) accs[i] = (f32x4){0.f, 0.f, 0.f, 0.f};
#pragma unroll
    for (int ct = 0; ct < 4; ct++) {
      const int key = ct * 16 + l16;
#pragma unroll
      for (int s = 0; s < 2; s++) {
        const int c8 = s * 4 + lhi;
        bf16x8 bk = *(const bf16x8*)&Kl[key * 64 + ((c8 ^ (key & 7)) << 3)];
        accs[ct] = __builtin_amdgcn_mfma_f32_16x16x32_bf16(qf[s], bk, accs[ct], 0, 0, 0);
      }
    }

    // ---- online softmax (rows live in one 16-lane group) ----
    float pvals[4][4];
#pragma unroll
    for (int r = 0; r < 4; r++) {
      float mx = fmaxf(fmaxf(accs[0][r], accs[1][r]), fmaxf(accs[2][r], accs[3][r]));
#pragma unroll
      for (int off = 1; off < 16; off <<= 1) mx = fmaxf(mx, __shfl_xor(mx, off, 64));
      const float mnew = fmaxf(m_run[r], mx);
      const float scale = __expf(m_run[r] - mnew);
      float rs = 0.f;
#pragma unroll
      for (int ct = 0; ct < 4; ct++) {
        float e = __expf(accs[ct][r] - mnew);
        pvals[ct][r] = e; rs += e;
      }
#pragma unroll
      for (int off = 1; off < 16; off <<= 1) rs += __shfl_xor(rs, off, 64);
      l_run[r] = l_run[r] * scale + rs;
      m_run[r] = mnew;
#pragma unroll
      for (int ct = 0; ct < 4; ct++) acc_o[ct][r] *= scale;
    }

    // ---- P -> per-wave LDS (swizzled), then O += P @ V ----
#pragma unroll
    for (int ct = 0; ct < 4; ct++) {
#pragma unroll
      for (int r = 0; r < 4; r++) {
        const int row = lhi * 4 + r, col = ct * 16 + l16;
        Pl[w][row * 64 + (col ^ ((row & 7) << 3))] = (__bf16)pvals[ct][r];
      }
    }
#pragma unroll
    for (int s = 0; s < 2; s++) {
      const int c8 = s * 4 + lhi;
      bf16x8 pa = *(const bf16x8*)&Pl[w][l16 * 64 + ((c8 ^ (l16 & 7)) << 3)];
#pragma unroll
      for (int ct2 = 0; ct2 < 4; ct2++) {
        const int d = ct2 * 16 + l16;
        bf16x8 bv = *(const bf16x8*)&Vt[d * 64 + ((c8 ^ (d & 7)) << 3)];
        acc_o[ct2] = __builtin_amdgcn_mfma_f32_16x16x32_bf16(pa, bv, acc_o[ct2], 0, 0, 0);
      }
    }
  }

  // ---- epilogue: normalize and store ----
  float* ob = out + base + (size_t)(m * 64 + w * 16) * D_;
#pragma unroll
  for (int ct2 = 0; ct2 < 4; ct2++) {
#pragma unroll
    for (int r = 0; r < 4; r++) {
      const int row = lhi * 4 + r, col = ct2 * 16 + l16;
      ob[(size_t)row * D_ + col] = acc_o[ct2][r] / l_run[r];
    }
  }
}

extern "C" void kernel_launch(void* const* d_in, const int* in_sizes, int n_in,
                              void* d_out, int out_size, void* d_ws, size_t ws_size,
                              hipStream_t stream) {
  const float* q = (const float*)d_in[0];
  const float* k = (const float*)d_in[1];
  const float* v = (const float*)d_in[2];
  float* out = (float*)d_out;

  float* pq = (float*)d_ws;                               // 1024*64 f32
  float* pk = pq + (size_t)BH_ * NB_ * D_;                // 1024*64 f32
  int*   lut = (int*)(pk + (size_t)BH_ * NB_ * D_);       // 1024*16 i32

  hipLaunchKernelGGL(block_means_kernel, dim3(BH_ * NB_), dim3(256), 0, stream, q, k, pq, pk);
  hipLaunchKernelGGL(blockmap_kernel, dim3(BH_), dim3(256), 0, stream, pq, pk, lut);
  hipLaunchKernelGGL(sparse_attn_kernel, dim3(BH_ * NB_), dim3(256), 0, stream, q, k, v, lut, out);
}

// Round 2
// 108.882 us; speedup vs baseline: 2.2646x; 2.2646x over previous
//
#include <hip/hip_runtime.h>
#include <hip/hip_bf16.h>

#define B_ 2
#define H_ 8
#define L_ 4096
#define D_ 64
#define NB_ 64
#define TOPK_ 16
#define BH_ 16

typedef __bf16 bf16x8 __attribute__((ext_vector_type(8)));
typedef float f32x4 __attribute__((ext_vector_type(4)));

// ---------------------------------------------------------------------------
// Kernel 1: per-block means of q and k.  grid = BH_*NB_ blocks, 256 threads.
// pq[bh*NB_*D_ + m*D_ + d], pk likewise (pk is UNcentered block mean).
// ---------------------------------------------------------------------------
__global__ __launch_bounds__(256) void block_means_kernel(
    const float* __restrict__ q, const float* __restrict__ k,
    float* __restrict__ pq, float* __restrict__ pk) {
  const int blk = blockIdx.x;          // bh*64 + m
  const int bh = blk >> 6, m = blk & 63;
  const int d = threadIdx.x & 63, g = threadIdx.x >> 6;   // g in 0..3
  const float* qb = q + ((size_t)bh * L_ + m * 64 + g * 16) * D_ + d;
  const float* kb = k + ((size_t)bh * L_ + m * 64 + g * 16) * D_ + d;
  float sq = 0.f, sk = 0.f;
#pragma unroll
  for (int i = 0; i < 16; i++) { sq += qb[(size_t)i * D_]; sk += kb[(size_t)i * D_]; }
  __shared__ float bufq[4][64];
  __shared__ float bufk[4][64];
  bufq[g][d] = sq; bufk[g][d] = sk;
  __syncthreads();
  if (g == 0) {
    float tq = bufq[0][d] + bufq[1][d] + bufq[2][d] + bufq[3][d];
    float tk = bufk[0][d] + bufk[1][d] + bufk[2][d] + bufk[3][d];
    pq[(size_t)blk * 64 + d] = tq * (1.f / 64.f);
    pk[(size_t)blk * 64 + d] = tk * (1.f / 64.f);
  }
}

// ---------------------------------------------------------------------------
// Kernel 2: scores = pq . (pk - mean_m(pk)), top-16 per row by RANK COUNTING
// (no serial argmax).  grid = BH_*4 (bh x row-quarter), 256 threads = 4 waves,
// each wave computes 4 rows.  Lane = candidate block index.  All fp32
// (selection must match the numpy reference; rank reproduces top_k's
// descending-value, lowest-index-on-tie order exactly).
// ---------------------------------------------------------------------------
__global__ __launch_bounds__(256) void blockmap_kernel(
    const float* __restrict__ pq, const float* __restrict__ pk,
    int* __restrict__ lut) {
  const int g = blockIdx.x;            // bh*4 + quarter
  const int bh = g >> 2, q4 = g & 3;
  const int t = threadIdx.x;
  const int lane = t & 63, w = t >> 6;

  __shared__ float s_pk[64][65];       // +1 pad: conflict-free row reads
  __shared__ float s_km[64];
  __shared__ float s_pq[16][64];
  __shared__ float s_sc[4][64];

#pragma unroll
  for (int i = 0; i < 16; i++) {
    int idx = i * 256 + t;
    s_pk[idx >> 6][idx & 63] = pk[(size_t)bh * 4096 + idx];
  }
#pragma unroll
  for (int i = 0; i < 4; i++) {
    int idx = i * 256 + t;
    s_pq[idx >> 6][idx & 63] = pq[(size_t)bh * 4096 + q4 * 1024 + idx];
  }
  __syncthreads();
  if (t < 64) {
    float s = 0.f;
#pragma unroll 8
    for (int r = 0; r < 64; r++) s += s_pk[r][t];
    s_km[t] = s * (1.f / 64.f);
  }
  __syncthreads();

#pragma unroll
  for (int rr = 0; rr < 4; rr++) {
    const int row = w * 4 + rr;        // local row 0..15
    float sc = 0.f;
#pragma unroll 8
    for (int d2 = 0; d2 < 64; ++d2)
      sc += s_pq[row][d2] * (s_pk[lane][d2] - s_km[d2]);
    s_sc[w][lane] = sc;
    __syncthreads();
    int rank = 0;
#pragma unroll 8
    for (int j = 0; j < 64; j++) {
      float o = s_sc[w][j];
      rank += (o > sc) || (o == sc && j < lane);
    }
    if (rank < TOPK_)
      lut[((size_t)bh * 64 + q4 * 16 + row) * TOPK_ + rank] = lane;
    __syncthreads();
  }
}

// ---------------------------------------------------------------------------
// Kernel 3: sparse flash attention over the selected blocks.
// grid = BH_*NB_ (one block per (bh, q-block)), 256 threads = 4 waves.
// Wave w owns q rows [w*16, w*16+16), all 64 output dims.
// LDS: K (swizzled [key][d]), V transposed (swizzled [d][key]), per-wave P.
// Swizzle: 16B chunk index ^= (row & 7)  (G4 fix for 128B-stride rows).
// ---------------------------------------------------------------------------
__global__ __launch_bounds__(256) void sparse_attn_kernel(
    const float* __restrict__ q, const float* __restrict__ k,
    const float* __restrict__ v, const int* __restrict__ lut,
    float* __restrict__ out) {
  const int blk = blockIdx.x;
  const int bh = blk >> 6, m = blk & 63;
  const int tid = threadIdx.x;
  const int lane = tid & 63;
  const int w = tid >> 6;
  const int l16 = lane & 15, lhi = lane >> 4;

  __shared__ __align__(16) __bf16 Kl[64 * 64];
  __shared__ __align__(16) __bf16 Vt[64 * 64];
  __shared__ __align__(16) __bf16 Pl[4][16 * 64];

  const size_t base = (size_t)bh * L_ * D_;

  // Q A-fragments, qk_scale folded in (0.125 = 2^-3, exact in bf16 rounding)
  bf16x8 qf[2];
  {
    const float* qrow = q + base + (size_t)(m * 64 + w * 16 + l16) * D_;
#pragma unroll
    for (int s = 0; s < 2; s++) {
      const float* p0 = qrow + s * 32 + lhi * 8;
      float4 a = *(const float4*)p0;
      float4 b = *(const float4*)(p0 + 4);
      bf16x8 f;
      f[0] = (__bf16)(a.x * 0.125f); f[1] = (__bf16)(a.y * 0.125f);
      f[2] = (__bf16)(a.z * 0.125f); f[3] = (__bf16)(a.w * 0.125f);
      f[4] = (__bf16)(b.x * 0.125f); f[5] = (__bf16)(b.y * 0.125f);
      f[6] = (__bf16)(b.z * 0.125f); f[7] = (__bf16)(b.w * 0.125f);
      qf[s] = f;
    }
  }

  f32x4 acc_o[4];
#pragma unroll
  for (int i = 0; i < 4; i++) acc_o[i] = (f32x4){0.f, 0.f, 0.f, 0.f};
  float m_run[4] = {-__builtin_inff(), -__builtin_inff(), -__builtin_inff(), -__builtin_inff()};
  float l_run[4] = {0.f, 0.f, 0.f, 0.f};

  const int srow = tid >> 2;          // staging row (= key index), 0..63
  const int sc16 = (tid & 3) * 16;    // staging col base (d)

  for (int it = 0; it < TOPK_; ++it) {
    const int kb = lut[(size_t)blk * TOPK_ + it];
    __syncthreads();   // previous iter's LDS reads are complete (consumed by MFMA)
    {
      const float* ks = k + base + (size_t)(kb * 64 + srow) * D_ + sc16;
      const float* vs = v + base + (size_t)(kb * 64 + srow) * D_ + sc16;
      float kf[16], vf[16];
#pragma unroll
      for (int h = 0; h < 4; h++) {
        float4 t4 = *(const float4*)(ks + h * 4);
        kf[h * 4 + 0] = t4.x; kf[h * 4 + 1] = t4.y; kf[h * 4 + 2] = t4.z; kf[h * 4 + 3] = t4.w;
        float4 u4 = *(const float4*)(vs + h * 4);
        vf[h * 4 + 0] = u4.x; vf[h * 4 + 1] = u4.y; vf[h * 4 + 2] = u4.z; vf[h * 4 + 3] = u4.w;
      }
#pragma unroll
      for (int h = 0; h < 2; h++) {
        int c8 = (sc16 >> 3) + h;
        bf16x8 kw;
#pragma unroll
        for (int j = 0; j < 8; j++) kw[j] = (__bf16)kf[h * 8 + j];
        *(bf16x8*)&Kl[srow * 64 + ((c8 ^ (srow & 7)) << 3)] = kw;
      }
#pragma unroll
      for (int i = 0; i < 16; i++) {
        int d = sc16 + i;
        Vt[d * 64 + (srow ^ ((d & 7) << 3))] = (__bf16)vf[i];
      }
    }
    __syncthreads();

    // ---- S = Q @ K^T (4 key-tiles of 16) ----
    f32x4 accs[4];
#pragma unroll
    for (int i = 0; i < 4; i++) accs[i] = (f32x4){0.f, 0.f, 0.f, 0.f};
#pragma unroll
    for (int ct = 0; ct < 4; ct++) {
      const int key = ct * 16 + l16;
#pragma unroll
      for (int s = 0; s < 2; s++) {
        const int c8 = s * 4 + lhi;
        bf16x8 bk = *(const bf16x8*)&Kl[key * 64 + ((c8 ^ (key & 7)) << 3)];
        accs[ct] = __builtin_amdgcn_mfma_f32_16x16x32_bf16(qf[s], bk, accs[ct], 0, 0, 0);
      }
    }

    // ---- online softmax (rows live in one 16-lane group) ----
    float pvals[4][4];
#pragma unroll
    for (int r = 0; r < 4; r++) {
      float mx = fmaxf(fmaxf(accs[0][r], accs[1][r]), fmaxf(accs[2][r], accs[3][r]));
#pragma unroll
      for (int off = 1; off < 16; off <<= 1) mx = fmaxf(mx, __shfl_xor(mx, off, 64));
      const float mnew = fmaxf(m_run[r], mx);
      const float scale = __expf(m_run[r] - mnew);
      float rs = 0.f;
#pragma unroll
      for (int ct = 0; ct < 4; ct++) {
        float e = __expf(accs[ct][r] - mnew);
        pvals[ct][r] = e; rs += e;
      }
#pragma unroll
      for (int off = 1; off < 16; off <<= 1) rs += __shfl_xor(rs, off, 64);
      l_run[r] = l_run[r] * scale + rs;
      m_run[r] = mnew;
#pragma unroll
      for (int ct = 0; ct < 4; ct++) acc_o[ct][r] *= scale;
    }

    // ---- P -> per-wave LDS (swizzled), then O += P @ V ----
#pragma unroll
    for (int ct = 0; ct < 4; ct++) {
#pragma unroll
      for (int r = 0; r < 4; r++) {
        const int row = lhi * 4 + r, col = ct * 16 + l16;
        Pl[w][row * 64 + (col ^ ((row & 7) << 3))] = (__bf16)pvals[ct][r];
      }
    }
#pragma unroll
    for (int s = 0; s < 2; s++) {
      const int c8 = s * 4 + lhi;
      bf16x8 pa = *(const bf16x8*)&Pl[w][l16 * 64 + ((c8 ^ (l16 & 7)) << 3)];
#pragma unroll
      for (int ct2 = 0; ct2 < 4; ct2++) {
        const int d = ct2 * 16 + l16;
        bf16x8 bv = *(const bf16x8*)&Vt[d * 64 + ((c8 ^ (d & 7)) << 3)];
        acc_o[ct2] = __builtin_amdgcn_mfma_f32_16x16x32_bf16(pa, bv, acc_o[ct2], 0, 0, 0);
      }
    }
  }

  // ---- epilogue: normalize and store ----
  float* ob = out + base + (size_t)(m * 64 + w * 16) * D_;
#pragma unroll
  for (int ct2 = 0; ct2 < 4; ct2++) {
#pragma unroll
    for (int r = 0; r < 4; r++) {
      const int row = lhi * 4 + r, col = ct2 * 16 + l16;
      ob[(size_t)row * D_ + col] = acc_o[ct2][r] / l_run[r];
    }
  }
}

extern "C" void kernel_launch(void* const* d_in, const int* in_sizes, int n_in,
                              void* d_out, int out_size, void* d_ws, size_t ws_size,
                              hipStream_t stream) {
  const float* q = (const float*)d_in[0];
  const float* k = (const float*)d_in[1];
  const float* v = (const float*)d_in[2];
  float* out = (float*)d_out;

  float* pq = (float*)d_ws;                               // 1024*64 f32
  float* pk = pq + (size_t)BH_ * NB_ * D_;                // 1024*64 f32
  int*   lut = (int*)(pk + (size_t)BH_ * NB_ * D_);       // 1024*16 i32

  hipLaunchKernelGGL(block_means_kernel, dim3(BH_ * NB_), dim3(256), 0, stream, q, k, pq, pk);
  hipLaunchKernelGGL(blockmap_kernel, dim3(BH_ * 4), dim3(256), 0, stream, pq, pk, lut);
  hipLaunchKernelGGL(sparse_attn_kernel, dim3(BH_ * NB_), dim3(256), 0, stream, q, k, v, lut, out);
}

// Round 3
// 92.316 us; speedup vs baseline: 2.6709x; 1.1794x over previous
//
#include <hip/hip_runtime.h>
#include <hip/hip_bf16.h>

#define B_ 2
#define H_ 8
#define L_ 4096
#define D_ 64
#define NB_ 64
#define TOPK_ 16
#define BH_ 16

typedef __bf16 bf16x8 __attribute__((ext_vector_type(8)));
typedef float f32x4 __attribute__((ext_vector_type(4)));

__device__ __forceinline__ void async_copy16(void* lds, const void* g) {
  __builtin_amdgcn_global_load_lds(
      (const __attribute__((address_space(1))) void*)g,
      (__attribute__((address_space(3))) void*)lds, 16, 0, 0);
}

// ---------------------------------------------------------------------------
// Kernel 1: per-block means of q and k.  grid = BH_*NB_, 256 threads.
// ---------------------------------------------------------------------------
__global__ __launch_bounds__(256) void block_means_kernel(
    const float* __restrict__ q, const float* __restrict__ k,
    float* __restrict__ pq, float* __restrict__ pk) {
  const int blk = blockIdx.x;          // bh*64 + m
  const int bh = blk >> 6, m = blk & 63;
  const int d = threadIdx.x & 63, g = threadIdx.x >> 6;   // g in 0..3
  const float* qb = q + ((size_t)bh * L_ + m * 64 + g * 16) * D_ + d;
  const float* kb = k + ((size_t)bh * L_ + m * 64 + g * 16) * D_ + d;
  float sq = 0.f, sk = 0.f;
#pragma unroll
  for (int i = 0; i < 16; i++) { sq += qb[(size_t)i * D_]; sk += kb[(size_t)i * D_]; }
  __shared__ float bufq[4][64];
  __shared__ float bufk[4][64];
  bufq[g][d] = sq; bufk[g][d] = sk;
  __syncthreads();
  if (g == 0) {
    float tq = bufq[0][d] + bufq[1][d] + bufq[2][d] + bufq[3][d];
    float tk = bufk[0][d] + bufk[1][d] + bufk[2][d] + bufk[3][d];
    pq[(size_t)blk * 64 + d] = tq * (1.f / 64.f);
    pk[(size_t)blk * 64 + d] = tk * (1.f / 64.f);
  }
}

// ---------------------------------------------------------------------------
// Kernel 2: scores + top-16 per row by rank counting (fp32, matches np top_k
// ordering incl. lowest-index tie-break).  grid = BH_*4, 256 threads.
// ---------------------------------------------------------------------------
__global__ __launch_bounds__(256) void blockmap_kernel(
    const float* __restrict__ pq, const float* __restrict__ pk,
    int* __restrict__ lut) {
  const int g = blockIdx.x;            // bh*4 + quarter
  const int bh = g >> 2, q4 = g & 3;
  const int t = threadIdx.x;
  const int lane = t & 63, w = t >> 6;

  __shared__ float s_pk[64][65];
  __shared__ float s_km[64];
  __shared__ float s_pq[16][64];
  __shared__ float s_sc[4][64];

#pragma unroll
  for (int i = 0; i < 16; i++) {
    int idx = i * 256 + t;
    s_pk[idx >> 6][idx & 63] = pk[(size_t)bh * 4096 + idx];
  }
#pragma unroll
  for (int i = 0; i < 4; i++) {
    int idx = i * 256 + t;
    s_pq[idx >> 6][idx & 63] = pq[(size_t)bh * 4096 + q4 * 1024 + idx];
  }
  __syncthreads();
  if (t < 64) {
    float s = 0.f;
#pragma unroll 8
    for (int r = 0; r < 64; r++) s += s_pk[r][t];
    s_km[t] = s * (1.f / 64.f);
  }
  __syncthreads();

#pragma unroll
  for (int rr = 0; rr < 4; rr++) {
    const int row = w * 4 + rr;        // local row 0..15
    float sc = 0.f;
#pragma unroll 8
    for (int d2 = 0; d2 < 64; ++d2)
      sc += s_pq[row][d2] * (s_pk[lane][d2] - s_km[d2]);
    s_sc[w][lane] = sc;
    __syncthreads();
    int rank = 0;
#pragma unroll 8
    for (int j = 0; j < 64; j++) {
      float o = s_sc[w][j];
      rank += (o > sc) || (o == sc && j < lane);
    }
    if (rank < TOPK_)
      lut[((size_t)bh * 64 + q4 * 16 + row) * TOPK_ + rank] = lane;
    __syncthreads();
  }
}

// ---------------------------------------------------------------------------
// Kernel 2.5 (fast path): pre-convert K -> bf16 swizzled LDS image, and
// V -> bf16 TRANSPOSED+swizzled LDS image, per source block (8 KB each,
// contiguous).  Paid once per k-block instead of once per gather (~16x).
// grid = BH_*NB_, 256 threads.  base of block blk is blk*4096 elements.
// ---------------------------------------------------------------------------
__global__ __launch_bounds__(256) void prep_kv_kernel(
    const float* __restrict__ k, const float* __restrict__ v,
    __bf16* __restrict__ kswz, __bf16* __restrict__ vtswz) {
  const int blk = blockIdx.x;
  const int tid = threadIdx.x;
  const int srow = tid >> 2;           // key row 0..63
  const int sc16 = (tid & 3) * 16;     // d col base

  const float* ks = k + (size_t)blk * 4096 + srow * 64 + sc16;
  const float* vs = v + (size_t)blk * 4096 + srow * 64 + sc16;
  float kf[16], vf[16];
#pragma unroll
  for (int h = 0; h < 4; h++) {
    float4 t4 = *(const float4*)(ks + h * 4);
    kf[h * 4 + 0] = t4.x; kf[h * 4 + 1] = t4.y; kf[h * 4 + 2] = t4.z; kf[h * 4 + 3] = t4.w;
    float4 u4 = *(const float4*)(vs + h * 4);
    vf[h * 4 + 0] = u4.x; vf[h * 4 + 1] = u4.y; vf[h * 4 + 2] = u4.z; vf[h * 4 + 3] = u4.w;
  }

  // K image: element index srow*64 + ((c8 ^ (srow&7))<<3)
  __bf16* gk = kswz + (size_t)blk * 4096;
#pragma unroll
  for (int h = 0; h < 2; h++) {
    int c8 = (sc16 >> 3) + h;
    bf16x8 kw;
#pragma unroll
    for (int j = 0; j < 8; j++) kw[j] = (__bf16)kf[h * 8 + j];
    *(bf16x8*)(gk + srow * 64 + ((c8 ^ (srow & 7)) << 3)) = kw;
  }

  // V image: transpose through LDS, then linear copy-out (coalesced).
  __shared__ __align__(16) __bf16 s_vt[4096];
#pragma unroll
  for (int i = 0; i < 16; i++) {
    int d = sc16 + i;
    s_vt[d * 64 + (srow ^ ((d & 7) << 3))] = (__bf16)vf[i];
  }
  __syncthreads();
  __bf16* gv = vtswz + (size_t)blk * 4096;
  *(bf16x8*)(gv + tid * 8)        = *(const bf16x8*)(s_vt + tid * 8);
  *(bf16x8*)(gv + 2048 + tid * 8) = *(const bf16x8*)(s_vt + 2048 + tid * 8);
}

// ---------------------------------------------------------------------------
// Kernel 3 (fast path): sparse flash attention over pre-swizzled bf16 K/V
// images.  grid = BH_*NB_, 256 threads = 4 waves; wave w owns q rows
// [w*16, w*16+16).  Double-buffered global_load_lds staging (T3 2-phase):
// STAGE(next) -> compute(cur) -> __syncthreads (drains vmcnt+lgkm).
// LDS image is a verbatim byte copy of the global image (linear dest,
// source pre-swizzled) so reads use the same XOR swizzle as before.
// ---------------------------------------------------------------------------
__global__ __launch_bounds__(256) void sparse_attn_fast(
    const float* __restrict__ q, const __bf16* __restrict__ kswz,
    const __bf16* __restrict__ vtswz, const int* __restrict__ lut,
    float* __restrict__ out) {
  const int blk = blockIdx.x;
  const int bh = blk >> 6, m = blk & 63;
  const int tid = threadIdx.x;
  const int lane = tid & 63;
  const int w = tid >> 6;
  const int l16 = lane & 15, lhi = lane >> 4;

  __shared__ __align__(16) __bf16 KV[2][8192];   // [buf][ K:0..4095 | V:4096..8191 ]
  __shared__ __align__(16) __bf16 Pl[4][1024];

  const size_t base = (size_t)bh * L_ * D_;

  // Q A-fragments, qk_scale 0.125 folded in (power of two, exact)
  bf16x8 qf[2];
  {
    const float* qrow = q + base + (size_t)(m * 64 + w * 16 + l16) * D_;
#pragma unroll
    for (int s = 0; s < 2; s++) {
      const float* p0 = qrow + s * 32 + lhi * 8;
      float4 a = *(const float4*)p0;
      float4 b = *(const float4*)(p0 + 4);
      bf16x8 f;
      f[0] = (__bf16)(a.x * 0.125f); f[1] = (__bf16)(a.y * 0.125f);
      f[2] = (__bf16)(a.z * 0.125f); f[3] = (__bf16)(a.w * 0.125f);
      f[4] = (__bf16)(b.x * 0.125f); f[5] = (__bf16)(b.y * 0.125f);
      f[6] = (__bf16)(b.z * 0.125f); f[7] = (__bf16)(b.w * 0.125f);
      qf[s] = f;
    }
  }

  f32x4 acc_o[4];
#pragma unroll
  for (int i = 0; i < 4; i++) acc_o[i] = (f32x4){0.f, 0.f, 0.f, 0.f};
  float m_run[4] = {-__builtin_inff(), -__builtin_inff(), -__builtin_inff(), -__builtin_inff()};
  float l_run[4] = {0.f, 0.f, 0.f, 0.f};

  // STAGE: 4 x global_load_lds dwordx4 per thread; lds base wave-uniform,
  // HW writes lane*16B; global src = image + tid*16B per 4KB issue.
  auto stage = [&](int b, int kb) {
    const __bf16* gk = kswz + ((size_t)(bh * 64 + kb)) * 4096;
    const __bf16* gv = vtswz + ((size_t)(bh * 64 + kb)) * 4096;
    async_copy16(&KV[b][0 * 2048 + w * 512], gk + 0 * 2048 + tid * 8);
    async_copy16(&KV[b][1 * 2048 + w * 512], gk + 1 * 2048 + tid * 8);
    async_copy16(&KV[b][4096 + 0 * 2048 + w * 512], gv + 0 * 2048 + tid * 8);
    async_copy16(&KV[b][4096 + 1 * 2048 + w * 512], gv + 1 * 2048 + tid * 8);
  };

  const size_t lutbase = (size_t)blk * TOPK_;
  stage(0, lut[lutbase]);
  __syncthreads();

  for (int it = 0; it < TOPK_; ++it) {
    const int cur = it & 1;
    if (it + 1 < TOPK_) stage(cur ^ 1, lut[lutbase + it + 1]);

    const __bf16* Kl = &KV[cur][0];
    const __bf16* Vt = &KV[cur][4096];

    // ---- S = Q @ K^T (4 key-tiles of 16) ----
    f32x4 accs[4];
#pragma unroll
    for (int i = 0; i < 4; i++) accs[i] = (f32x4){0.f, 0.f, 0.f, 0.f};
#pragma unroll
    for (int ct = 0; ct < 4; ct++) {
      const int key = ct * 16 + l16;
#pragma unroll
      for (int s = 0; s < 2; s++) {
        const int c8 = s * 4 + lhi;
        bf16x8 bk = *(const bf16x8*)&Kl[key * 64 + ((c8 ^ (key & 7)) << 3)];
        accs[ct] = __builtin_amdgcn_mfma_f32_16x16x32_bf16(qf[s], bk, accs[ct], 0, 0, 0);
      }
    }

    // ---- online softmax (each q-row lives in one 16-lane group) ----
    float pvals[4][4];
#pragma unroll
    for (int r = 0; r < 4; r++) {
      float mx = fmaxf(fmaxf(accs[0][r], accs[1][r]), fmaxf(accs[2][r], accs[3][r]));
#pragma unroll
      for (int off = 1; off < 16; off <<= 1) mx = fmaxf(mx, __shfl_xor(mx, off, 64));
      const float mnew = fmaxf(m_run[r], mx);
      const float scale = __expf(m_run[r] - mnew);
      float rs = 0.f;
#pragma unroll
      for (int ct = 0; ct < 4; ct++) {
        float e = __expf(accs[ct][r] - mnew);
        pvals[ct][r] = e; rs += e;
      }
#pragma unroll
      for (int off = 1; off < 16; off <<= 1) rs += __shfl_xor(rs, off, 64);
      l_run[r] = l_run[r] * scale + rs;
      m_run[r] = mnew;
#pragma unroll
      for (int ct = 0; ct < 4; ct++) acc_o[ct][r] *= scale;
    }

    // ---- P -> per-wave LDS (swizzled), then O += P @ V ----
#pragma unroll
    for (int ct = 0; ct < 4; ct++) {
#pragma unroll
      for (int r = 0; r < 4; r++) {
        const int row = lhi * 4 + r, col = ct * 16 + l16;
        Pl[w][row * 64 + (col ^ ((row & 7) << 3))] = (__bf16)pvals[ct][r];
      }
    }
#pragma unroll
    for (int s = 0; s < 2; s++) {
      const int c8 = s * 4 + lhi;
      bf16x8 pa = *(const bf16x8*)&Pl[w][l16 * 64 + ((c8 ^ (l16 & 7)) << 3)];
#pragma unroll
      for (int ct2 = 0; ct2 < 4; ct2++) {
        const int d = ct2 * 16 + l16;
        bf16x8 bv = *(const bf16x8*)&Vt[d * 64 + ((c8 ^ (d & 7)) << 3)];
        acc_o[ct2] = __builtin_amdgcn_mfma_f32_16x16x32_bf16(pa, bv, acc_o[ct2], 0, 0, 0);
      }
    }

    __syncthreads();   // drains vmcnt(0): next buffer staged; all reads of cur done
  }

  // ---- epilogue: normalize and store ----
  float* ob = out + base + (size_t)(m * 64 + w * 16) * D_;
#pragma unroll
  for (int ct2 = 0; ct2 < 4; ct2++) {
#pragma unroll
    for (int r = 0; r < 4; r++) {
      const int row = lhi * 4 + r, col = ct2 * 16 + l16;
      ob[(size_t)row * D_ + col] = acc_o[ct2][r] / l_run[r];
    }
  }
}

// ---------------------------------------------------------------------------
// Kernel 3 (fallback, round-2 version): used only if ws_size can't hold the
// pre-converted K/V images.  In-kernel fp32 gather + convert + transpose.
// ---------------------------------------------------------------------------
__global__ __launch_bounds__(256) void sparse_attn_slow(
    const float* __restrict__ q, const float* __restrict__ k,
    const float* __restrict__ v, const int* __restrict__ lut,
    float* __restrict__ out) {
  const int blk = blockIdx.x;
  const int bh = blk >> 6, m = blk & 63;
  const int tid = threadIdx.x;
  const int lane = tid & 63;
  const int w = tid >> 6;
  const int l16 = lane & 15, lhi = lane >> 4;

  __shared__ __align__(16) __bf16 Kl[64 * 64];
  __shared__ __align__(16) __bf16 Vt[64 * 64];
  __shared__ __align__(16) __bf16 Pl[4][16 * 64];

  const size_t base = (size_t)bh * L_ * D_;

  bf16x8 qf[2];
  {
    const float* qrow = q + base + (size_t)(m * 64 + w * 16 + l16) * D_;
#pragma unroll
    for (int s = 0; s < 2; s++) {
      const float* p0 = qrow + s * 32 + lhi * 8;
      float4 a = *(const float4*)p0;
      float4 b = *(const float4*)(p0 + 4);
      bf16x8 f;
      f[0] = (__bf16)(a.x * 0.125f); f[1] = (__bf16)(a.y * 0.125f);
      f[2] = (__bf16)(a.z * 0.125f); f[3] = (__bf16)(a.w * 0.125f);
      f[4] = (__bf16)(b.x * 0.125f); f[5] = (__bf16)(b.y * 0.125f);
      f[6] = (__bf16)(b.z * 0.125f); f[7] = (__bf16)(b.w * 0.125f);
      qf[s] = f;
    }
  }

  f32x4 acc_o[4];
#pragma unroll
  for (int i = 0; i < 4; i++) acc_o[i] = (f32x4){0.f, 0.f, 0.f, 0.f};
  float m_run[4] = {-__builtin_inff(), -__builtin_inff(), -__builtin_inff(), -__builtin_inff()};
  float l_run[4] = {0.f, 0.f, 0.f, 0.f};

  const int srow = tid >> 2;
  const int sc16 = (tid & 3) * 16;

  for (int it = 0; it < TOPK_; ++it) {
    const int kb = lut[(size_t)blk * TOPK_ + it];
    __syncthreads();
    {
      const float* ks = k + base + (size_t)(kb * 64 + srow) * D_ + sc16;
      const float* vs = v + base + (size_t)(kb * 64 + srow) * D_ + sc16;
      float kf[16], vf[16];
#pragma unroll
      for (int h = 0; h < 4; h++) {
        float4 t4 = *(const float4*)(ks + h * 4);
        kf[h * 4 + 0] = t4.x; kf[h * 4 + 1] = t4.y; kf[h * 4 + 2] = t4.z; kf[h * 4 + 3] = t4.w;
        float4 u4 = *(const float4*)(vs + h * 4);
        vf[h * 4 + 0] = u4.x; vf[h * 4 + 1] = u4.y; vf[h * 4 + 2] = u4.z; vf[h * 4 + 3] = u4.w;
      }
#pragma unroll
      for (int h = 0; h < 2; h++) {
        int c8 = (sc16 >> 3) + h;
        bf16x8 kw;
#pragma unroll
        for (int j = 0; j < 8; j++) kw[j] = (__bf16)kf[h * 8 + j];
        *(bf16x8*)&Kl[srow * 64 + ((c8 ^ (srow & 7)) << 3)] = kw;
      }
#pragma unroll
      for (int i = 0; i < 16; i++) {
        int d = sc16 + i;
        Vt[d * 64 + (srow ^ ((d & 7) << 3))] = (__bf16)vf[i];
      }
    }
    __syncthreads();

    f32x4 accs[4];
#pragma unroll
    for (int i = 0; i < 4; i++) accs[i] = (f32x4){0.f, 0.f, 0.f, 0.f};
#pragma unroll
    for (int ct = 0; ct < 4; ct++) {
      const int key = ct * 16 + l16;
#pragma unroll
      for (int s = 0; s < 2; s++) {
        const int c8 = s * 4 + lhi;
        bf16x8 bk = *(const bf16x8*)&Kl[key * 64 + ((c8 ^ (key & 7)) << 3)];
        accs[ct] = __builtin_amdgcn_mfma_f32_16x16x32_bf16(qf[s], bk, accs[ct], 0, 0, 0);
      }
    }

    float pvals[4][4];
#pragma unroll
    for (int r = 0; r < 4; r++) {
      float mx = fmaxf(fmaxf(accs[0][r], accs[1][r]), fmaxf(accs[2][r], accs[3][r]));
#pragma unroll
      for (int off = 1; off < 16; off <<= 1) mx = fmaxf(mx, __shfl_xor(mx, off, 64));
      const float mnew = fmaxf(m_run[r], mx);
      const float scale = __expf(m_run[r] - mnew);
      float rs = 0.f;
#pragma unroll
      for (int ct = 0; ct < 4; ct++) {
        float e = __expf(accs[ct][r] - mnew);
        pvals[ct][r] = e; rs += e;
      }
#pragma unroll
      for (int off = 1; off < 16; off <<= 1) rs += __shfl_xor(rs, off, 64);
      l_run[r] = l_run[r] * scale + rs;
      m_run[r] = mnew;
#pragma unroll
      for (int ct = 0; ct < 4; ct++) acc_o[ct][r] *= scale;
    }

#pragma unroll
    for (int ct = 0; ct < 4; ct++) {
#pragma unroll
      for (int r = 0; r < 4; r++) {
        const int row = lhi * 4 + r, col = ct * 16 + l16;
        Pl[w][row * 64 + (col ^ ((row & 7) << 3))] = (__bf16)pvals[ct][r];
      }
    }
#pragma unroll
    for (int s = 0; s < 2; s++) {
      const int c8 = s * 4 + lhi;
      bf16x8 pa = *(const bf16x8*)&Pl[w][l16 * 64 + ((c8 ^ (l16 & 7)) << 3)];
#pragma unroll
      for (int ct2 = 0; ct2 < 4; ct2++) {
        const int d = ct2 * 16 + l16;
        bf16x8 bv = *(const bf16x8*)&Vt[d * 64 + ((c8 ^ (d & 7)) << 3)];
        acc_o[ct2] = __builtin_amdgcn_mfma_f32_16x16x32_bf16(pa, bv, acc_o[ct2], 0, 0, 0);
      }
    }
  }

  float* ob = out + base + (size_t)(m * 64 + w * 16) * D_;
#pragma unroll
  for (int ct2 = 0; ct2 < 4; ct2++) {
#pragma unroll
    for (int r = 0; r < 4; r++) {
      const int row = lhi * 4 + r, col = ct2 * 16 + l16;
      ob[(size_t)row * D_ + col] = acc_o[ct2][r] / l_run[r];
    }
  }
}

extern "C" void kernel_launch(void* const* d_in, const int* in_sizes, int n_in,
                              void* d_out, int out_size, void* d_ws, size_t ws_size,
                              hipStream_t stream) {
  const float* q = (const float*)d_in[0];
  const float* k = (const float*)d_in[1];
  const float* v = (const float*)d_in[2];
  float* out = (float*)d_out;

  // ws layout: pq (256KB) | pk (256KB) | lut (64KB) | Kswz (8MB) | Vtswz (8MB)
  float* pq = (float*)d_ws;
  float* pk = pq + (size_t)BH_ * NB_ * D_;
  int*   lut = (int*)(pk + (size_t)BH_ * NB_ * D_);
  char*  extra = (char*)(lut + (size_t)BH_ * NB_ * TOPK_);
  __bf16* kswz = (__bf16*)extra;
  __bf16* vtswz = kswz + (size_t)BH_ * NB_ * 4096;

  const size_t needed = (size_t)((char*)(vtswz + (size_t)BH_ * NB_ * 4096) - (char*)d_ws);
  const bool fast = ws_size >= needed;

  hipLaunchKernelGGL(block_means_kernel, dim3(BH_ * NB_), dim3(256), 0, stream, q, k, pq, pk);
  hipLaunchKernelGGL(blockmap_kernel, dim3(BH_ * 4), dim3(256), 0, stream, pq, pk, lut);
  if (fast) {
    hipLaunchKernelGGL(prep_kv_kernel, dim3(BH_ * NB_), dim3(256), 0, stream, k, v, kswz, vtswz);
    hipLaunchKernelGGL(sparse_attn_fast, dim3(BH_ * NB_), dim3(256), 0, stream, q, kswz, vtswz, lut, out);
  } else {
    hipLaunchKernelGGL(sparse_attn_slow, dim3(BH_ * NB_), dim3(256), 0, stream, q, k, v, lut, out);
  }
}

// Round 4
// 77.166 us; speedup vs baseline: 3.1953x; 1.1963x over previous
//
#include <hip/hip_runtime.h>
#include <hip/hip_bf16.h>

#define B_ 2
#define H_ 8
#define L_ 4096
#define D_ 64
#define NB_ 64
#define TOPK_ 16
#define BH_ 16

typedef __bf16 bf16x8 __attribute__((ext_vector_type(8)));
typedef float f32x4 __attribute__((ext_vector_type(4)));

__device__ __forceinline__ void async_copy16(void* lds, const void* g) {
  __builtin_amdgcn_global_load_lds(
      (const __attribute__((address_space(1))) void*)g,
      (__attribute__((address_space(3))) void*)lds, 16, 0, 0);
}

// ---------------------------------------------------------------------------
// Kernel 1: per-block means of q and k.  grid = BH_*NB_, 256 threads.
// ---------------------------------------------------------------------------
__global__ __launch_bounds__(256) void block_means_kernel(
    const float* __restrict__ q, const float* __restrict__ k,
    float* __restrict__ pq, float* __restrict__ pk) {
  const int blk = blockIdx.x;          // bh*64 + m
  const int bh = blk >> 6, m = blk & 63;
  const int d = threadIdx.x & 63, g = threadIdx.x >> 6;   // g in 0..3
  const float* qb = q + ((size_t)bh * L_ + m * 64 + g * 16) * D_ + d;
  const float* kb = k + ((size_t)bh * L_ + m * 64 + g * 16) * D_ + d;
  float sq = 0.f, sk = 0.f;
#pragma unroll
  for (int i = 0; i < 16; i++) { sq += qb[(size_t)i * D_]; sk += kb[(size_t)i * D_]; }
  __shared__ float bufq[4][64];
  __shared__ float bufk[4][64];
  bufq[g][d] = sq; bufk[g][d] = sk;
  __syncthreads();
  if (g == 0) {
    float tq = bufq[0][d] + bufq[1][d] + bufq[2][d] + bufq[3][d];
    float tk = bufk[0][d] + bufk[1][d] + bufk[2][d] + bufk[3][d];
    pq[(size_t)blk * 64 + d] = tq * (1.f / 64.f);
    pk[(size_t)blk * 64 + d] = tk * (1.f / 64.f);
  }
}

// ---------------------------------------------------------------------------
// Kernel 2: scores + top-16 per row by rank counting (fp32, matches np top_k
// ordering incl. lowest-index tie-break).  grid = BH_*4, 256 threads.
// ---------------------------------------------------------------------------
__global__ __launch_bounds__(256) void blockmap_kernel(
    const float* __restrict__ pq, const float* __restrict__ pk,
    int* __restrict__ lut) {
  const int g = blockIdx.x;            // bh*4 + quarter
  const int bh = g >> 2, q4 = g & 3;
  const int t = threadIdx.x;
  const int lane = t & 63, w = t >> 6;

  __shared__ float s_pk[64][65];
  __shared__ float s_km[64];
  __shared__ float s_pq[16][64];
  __shared__ float s_sc[4][64];

#pragma unroll
  for (int i = 0; i < 16; i++) {
    int idx = i * 256 + t;
    s_pk[idx >> 6][idx & 63] = pk[(size_t)bh * 4096 + idx];
  }
#pragma unroll
  for (int i = 0; i < 4; i++) {
    int idx = i * 256 + t;
    s_pq[idx >> 6][idx & 63] = pq[(size_t)bh * 4096 + q4 * 1024 + idx];
  }
  __syncthreads();
  if (t < 64) {
    float s = 0.f;
#pragma unroll 8
    for (int r = 0; r < 64; r++) s += s_pk[r][t];
    s_km[t] = s * (1.f / 64.f);
  }
  __syncthreads();

#pragma unroll
  for (int rr = 0; rr < 4; rr++) {
    const int row = w * 4 + rr;        // local row 0..15
    float sc = 0.f;
#pragma unroll 8
    for (int d2 = 0; d2 < 64; ++d2)
      sc += s_pq[row][d2] * (s_pk[lane][d2] - s_km[d2]);
    s_sc[w][lane] = sc;
    __syncthreads();
    int rank = 0;
#pragma unroll 8
    for (int j = 0; j < 64; j++) {
      float o = s_sc[w][j];
      rank += (o > sc) || (o == sc && j < lane);
    }
    if (rank < TOPK_)
      lut[((size_t)bh * 64 + q4 * 16 + row) * TOPK_ + rank] = lane;
    __syncthreads();
  }
}

// ---------------------------------------------------------------------------
// Kernel 2.5: pre-convert K -> bf16 swizzled LDS image, V -> bf16
// TRANSPOSED+swizzled LDS image, per source block (8 KB each, contiguous).
// Paid once per k-block instead of once per gather (~16x).
// ---------------------------------------------------------------------------
__global__ __launch_bounds__(256) void prep_kv_kernel(
    const float* __restrict__ k, const float* __restrict__ v,
    __bf16* __restrict__ kswz, __bf16* __restrict__ vtswz) {
  const int blk = blockIdx.x;
  const int tid = threadIdx.x;
  const int srow = tid >> 2;           // key row 0..63
  const int sc16 = (tid & 3) * 16;     // d col base

  const float* ks = k + (size_t)blk * 4096 + srow * 64 + sc16;
  const float* vs = v + (size_t)blk * 4096 + srow * 64 + sc16;
  float kf[16], vf[16];
#pragma unroll
  for (int h = 0; h < 4; h++) {
    float4 t4 = *(const float4*)(ks + h * 4);
    kf[h * 4 + 0] = t4.x; kf[h * 4 + 1] = t4.y; kf[h * 4 + 2] = t4.z; kf[h * 4 + 3] = t4.w;
    float4 u4 = *(const float4*)(vs + h * 4);
    vf[h * 4 + 0] = u4.x; vf[h * 4 + 1] = u4.y; vf[h * 4 + 2] = u4.z; vf[h * 4 + 3] = u4.w;
  }

  __bf16* gk = kswz + (size_t)blk * 4096;
#pragma unroll
  for (int h = 0; h < 2; h++) {
    int c8 = (sc16 >> 3) + h;
    bf16x8 kw;
#pragma unroll
    for (int j = 0; j < 8; j++) kw[j] = (__bf16)kf[h * 8 + j];
    *(bf16x8*)(gk + srow * 64 + ((c8 ^ (srow & 7)) << 3)) = kw;
  }

  __shared__ __align__(16) __bf16 s_vt[4096];
#pragma unroll
  for (int i = 0; i < 16; i++) {
    int d = sc16 + i;
    s_vt[d * 64 + (srow ^ ((d & 7) << 3))] = (__bf16)vf[i];
  }
  __syncthreads();
  __bf16* gv = vtswz + (size_t)blk * 4096;
  *(bf16x8*)(gv + tid * 8)        = *(const bf16x8*)(s_vt + tid * 8);
  *(bf16x8*)(gv + 2048 + tid * 8) = *(const bf16x8*)(s_vt + 2048 + tid * 8);
}

// ---------------------------------------------------------------------------
// Kernel 3 (fast path): sparse flash attention over pre-swizzled bf16 K/V
// images.  grid = BH_*NB_, 256 threads = 4 waves; wave w owns q rows
// [w*16, w*16+16).  Double-buffered global_load_lds staging.
// Softmax in log2 domain with defer-max (T13): common path has NO cross-lane
// shuffles, NO rescale; l_run is a per-lane partial reduced in the epilogue.
// ---------------------------------------------------------------------------
__global__ __launch_bounds__(256) void sparse_attn_fast(
    const float* __restrict__ q, const __bf16* __restrict__ kswz,
    const __bf16* __restrict__ vtswz, const int* __restrict__ lut,
    float* __restrict__ out) {
  const int blk = blockIdx.x;
  const int bh = blk >> 6, m = blk & 63;
  const int tid = threadIdx.x;
  const int lane = tid & 63;
  const int w = tid >> 6;
  const int l16 = lane & 15, lhi = lane >> 4;

  __shared__ __align__(16) __bf16 KV[2][8192];   // [buf][ K:0..4095 | V:4096..8191 ]
  __shared__ __align__(16) __bf16 Pl[4][1024];

  const size_t base = (size_t)bh * L_ * D_;

  // Q A-fragments; qk_scale * log2(e) folded in (S computed in log2 domain)
  const float QSC = 0.125f * 1.44269504088896340736f;
  bf16x8 qf[2];
  {
    const float* qrow = q + base + (size_t)(m * 64 + w * 16 + l16) * D_;
#pragma unroll
    for (int s = 0; s < 2; s++) {
      const float* p0 = qrow + s * 32 + lhi * 8;
      float4 a = *(const float4*)p0;
      float4 b = *(const float4*)(p0 + 4);
      bf16x8 f;
      f[0] = (__bf16)(a.x * QSC); f[1] = (__bf16)(a.y * QSC);
      f[2] = (__bf16)(a.z * QSC); f[3] = (__bf16)(a.w * QSC);
      f[4] = (__bf16)(b.x * QSC); f[5] = (__bf16)(b.y * QSC);
      f[6] = (__bf16)(b.z * QSC); f[7] = (__bf16)(b.w * QSC);
      qf[s] = f;
    }
  }

  f32x4 acc_o[4];
#pragma unroll
  for (int i = 0; i < 4; i++) acc_o[i] = (f32x4){0.f, 0.f, 0.f, 0.f};
  float m_run[4] = {-__builtin_inff(), -__builtin_inff(), -__builtin_inff(), -__builtin_inff()};
  float l_run[4] = {0.f, 0.f, 0.f, 0.f};   // PER-LANE partial sums (log2 dom.)

  auto stage = [&](int b, int kb) {
    const __bf16* gk = kswz + ((size_t)(bh * 64 + kb)) * 4096;
    const __bf16* gv = vtswz + ((size_t)(bh * 64 + kb)) * 4096;
    async_copy16(&KV[b][0 * 2048 + w * 512], gk + 0 * 2048 + tid * 8);
    async_copy16(&KV[b][1 * 2048 + w * 512], gk + 1 * 2048 + tid * 8);
    async_copy16(&KV[b][4096 + 0 * 2048 + w * 512], gv + 0 * 2048 + tid * 8);
    async_copy16(&KV[b][4096 + 1 * 2048 + w * 512], gv + 1 * 2048 + tid * 8);
  };

  const size_t lutbase = (size_t)blk * TOPK_;
  stage(0, lut[lutbase]);
  __syncthreads();

  for (int it = 0; it < TOPK_; ++it) {
    const int cur = it & 1;
    if (it + 1 < TOPK_) stage(cur ^ 1, lut[lutbase + it + 1]);

    const __bf16* Kl = &KV[cur][0];
    const __bf16* Vt = &KV[cur][4096];

    // ---- S = Q @ K^T (log2 units; 4 key-tiles of 16) ----
    f32x4 accs[4];
#pragma unroll
    for (int i = 0; i < 4; i++) accs[i] = (f32x4){0.f, 0.f, 0.f, 0.f};
    __builtin_amdgcn_s_setprio(1);
#pragma unroll
    for (int ct = 0; ct < 4; ct++) {
      const int key = ct * 16 + l16;
#pragma unroll
      for (int s = 0; s < 2; s++) {
        const int c8 = s * 4 + lhi;
        bf16x8 bk = *(const bf16x8*)&Kl[key * 64 + ((c8 ^ (key & 7)) << 3)];
        accs[ct] = __builtin_amdgcn_mfma_f32_16x16x32_bf16(qf[s], bk, accs[ct], 0, 0, 0);
      }
    }
    __builtin_amdgcn_s_setprio(0);

    // ---- online softmax, log2 domain, defer-max (T13) ----
    float px[4];
    bool ok = true;
#pragma unroll
    for (int r = 0; r < 4; r++) {
      px[r] = fmaxf(fmaxf(accs[0][r], accs[1][r]), fmaxf(accs[2][r], accs[3][r]));
      ok = ok && (px[r] <= m_run[r] + 8.f);
    }
    if (!__all(ok)) {   // rare: full cross-lane max + rescale
#pragma unroll
      for (int r = 0; r < 4; r++) {
        float mx = px[r];
#pragma unroll
        for (int off = 1; off < 16; off <<= 1) mx = fmaxf(mx, __shfl_xor(mx, off, 64));
        const float mnew = fmaxf(m_run[r], mx);
        const float sc = exp2f(m_run[r] - mnew);
        l_run[r] *= sc;
#pragma unroll
        for (int ct = 0; ct < 4; ct++) acc_o[ct][r] *= sc;
        m_run[r] = mnew;
      }
    }
    float pvals[4][4];
#pragma unroll
    for (int r = 0; r < 4; r++) {
      float s = 0.f;
#pragma unroll
      for (int ct = 0; ct < 4; ct++) {
        float e = exp2f(accs[ct][r] - m_run[r]);   // bounded by 2^8
        pvals[ct][r] = e; s += e;
      }
      l_run[r] += s;
    }

    // ---- P -> per-wave LDS (swizzled), then O += P @ V ----
#pragma unroll
    for (int ct = 0; ct < 4; ct++) {
#pragma unroll
      for (int r = 0; r < 4; r++) {
        const int row = lhi * 4 + r, col = ct * 16 + l16;
        Pl[w][row * 64 + (col ^ ((row & 7) << 3))] = (__bf16)pvals[ct][r];
      }
    }
    __builtin_amdgcn_s_setprio(1);
#pragma unroll
    for (int s = 0; s < 2; s++) {
      const int c8 = s * 4 + lhi;
      bf16x8 pa = *(const bf16x8*)&Pl[w][l16 * 64 + ((c8 ^ (l16 & 7)) << 3)];
#pragma unroll
      for (int ct2 = 0; ct2 < 4; ct2++) {
        const int d = ct2 * 16 + l16;
        bf16x8 bv = *(const bf16x8*)&Vt[d * 64 + ((c8 ^ (d & 7)) << 3)];
        acc_o[ct2] = __builtin_amdgcn_mfma_f32_16x16x32_bf16(pa, bv, acc_o[ct2], 0, 0, 0);
      }
    }
    __builtin_amdgcn_s_setprio(0);

    __syncthreads();   // next buffer staged; all reads of cur done
  }

  // ---- epilogue: reduce per-lane l partials across the 16-lane group ----
#pragma unroll
  for (int r = 0; r < 4; r++) {
#pragma unroll
    for (int off = 1; off < 16; off <<= 1) l_run[r] += __shfl_xor(l_run[r], off, 64);
  }
  float* ob = out + base + (size_t)(m * 64 + w * 16) * D_;
#pragma unroll
  for (int ct2 = 0; ct2 < 4; ct2++) {
#pragma unroll
    for (int r = 0; r < 4; r++) {
      const int row = lhi * 4 + r, col = ct2 * 16 + l16;
      ob[(size_t)row * D_ + col] = acc_o[ct2][r] / l_run[r];
    }
  }
}

// ---------------------------------------------------------------------------
// Kernel 3 (fallback, round-2 version): only if ws_size too small.
// ---------------------------------------------------------------------------
__global__ __launch_bounds__(256) void sparse_attn_slow(
    const float* __restrict__ q, const float* __restrict__ k,
    const float* __restrict__ v, const int* __restrict__ lut,
    float* __restrict__ out) {
  const int blk = blockIdx.x;
  const int bh = blk >> 6, m = blk & 63;
  const int tid = threadIdx.x;
  const int lane = tid & 63;
  const int w = tid >> 6;
  const int l16 = lane & 15, lhi = lane >> 4;

  __shared__ __align__(16) __bf16 Kl[64 * 64];
  __shared__ __align__(16) __bf16 Vt[64 * 64];
  __shared__ __align__(16) __bf16 Pl[4][16 * 64];

  const size_t base = (size_t)bh * L_ * D_;

  bf16x8 qf[2];
  {
    const float* qrow = q + base + (size_t)(m * 64 + w * 16 + l16) * D_;
#pragma unroll
    for (int s = 0; s < 2; s++) {
      const float* p0 = qrow + s * 32 + lhi * 8;
      float4 a = *(const float4*)p0;
      float4 b = *(const float4*)(p0 + 4);
      bf16x8 f;
      f[0] = (__bf16)(a.x * 0.125f); f[1] = (__bf16)(a.y * 0.125f);
      f[2] = (__bf16)(a.z * 0.125f); f[3] = (__bf16)(a.w * 0.125f);
      f[4] = (__bf16)(b.x * 0.125f); f[5] = (__bf16)(b.y * 0.125f);
      f[6] = (__bf16)(b.z * 0.125f); f[7] = (__bf16)(b.w * 0.125f);
      qf[s] = f;
    }
  }

  f32x4 acc_o[4];
#pragma unroll
  for (int i = 0; i < 4; i++) acc_o[i] = (f32x4){0.f, 0.f, 0.f, 0.f};
  float m_run[4] = {-__builtin_inff(), -__builtin_inff(), -__builtin_inff(), -__builtin_inff()};
  float l_run[4] = {0.f, 0.f, 0.f, 0.f};

  const int srow = tid >> 2;
  const int sc16 = (tid & 3) * 16;

  for (int it = 0; it < TOPK_; ++it) {
    const int kb = lut[(size_t)blk * TOPK_ + it];
    __syncthreads();
    {
      const float* ks = k + base + (size_t)(kb * 64 + srow) * D_ + sc16;
      const float* vs = v + base + (size_t)(kb * 64 + srow) * D_ + sc16;
      float kf[16], vf[16];
#pragma unroll
      for (int h = 0; h < 4; h++) {
        float4 t4 = *(const float4*)(ks + h * 4);
        kf[h * 4 + 0] = t4.x; kf[h * 4 + 1] = t4.y; kf[h * 4 + 2] = t4.z; kf[h * 4 + 3] = t4.w;
        float4 u4 = *(const float4*)(vs + h * 4);
        vf[h * 4 + 0] = u4.x; vf[h * 4 + 1] = u4.y; vf[h * 4 + 2] = u4.z; vf[h * 4 + 3] = u4.w;
      }
#pragma unroll
      for (int h = 0; h < 2; h++) {
        int c8 = (sc16 >> 3) + h;
        bf16x8 kw;
#pragma unroll
        for (int j = 0; j < 8; j++) kw[j] = (__bf16)kf[h * 8 + j];
        *(bf16x8*)&Kl[srow * 64 + ((c8 ^ (srow & 7)) << 3)] = kw;
      }
#pragma unroll
      for (int i = 0; i < 16; i++) {
        int d = sc16 + i;
        Vt[d * 64 + (srow ^ ((d & 7) << 3))] = (__bf16)vf[i];
      }
    }
    __syncthreads();

    f32x4 accs[4];
#pragma unroll
    for (int i = 0; i < 4; i++) accs[i] = (f32x4){0.f, 0.f, 0.f, 0.f};
#pragma unroll
    for (int ct = 0; ct < 4; ct++) {
      const int key = ct * 16 + l16;
#pragma unroll
      for (int s = 0; s < 2; s++) {
        const int c8 = s * 4 + lhi;
        bf16x8 bk = *(const bf16x8*)&Kl[key * 64 + ((c8 ^ (key & 7)) << 3)];
        accs[ct] = __builtin_amdgcn_mfma_f32_16x16x32_bf16(qf[s], bk, accs[ct], 0, 0, 0);
      }
    }

    float pvals[4][4];
#pragma unroll
    for (int r = 0; r < 4; r++) {
      float mx = fmaxf(fmaxf(accs[0][r], accs[1][r]), fmaxf(accs[2][r], accs[3][r]));
#pragma unroll
      for (int off = 1; off < 16; off <<= 1) mx = fmaxf(mx, __shfl_xor(mx, off, 64));
      const float mnew = fmaxf(m_run[r], mx);
      const float scale = __expf(m_run[r] - mnew);
      float rs = 0.f;
#pragma unroll
      for (int ct = 0; ct < 4; ct++) {
        float e = __expf(accs[ct][r] - mnew);
        pvals[ct][r] = e; rs += e;
      }
#pragma unroll
      for (int off = 1; off < 16; off <<= 1) rs += __shfl_xor(rs, off, 64);
      l_run[r] = l_run[r] * scale + rs;
      m_run[r] = mnew;
#pragma unroll
      for (int ct = 0; ct < 4; ct++) acc_o[ct][r] *= scale;
    }

#pragma unroll
    for (int ct = 0; ct < 4; ct++) {
#pragma unroll
      for (int r = 0; r < 4; r++) {
        const int row = lhi * 4 + r, col = ct * 16 + l16;
        Pl[w][row * 64 + (col ^ ((row & 7) << 3))] = (__bf16)pvals[ct][r];
      }
    }
#pragma unroll
    for (int s = 0; s < 2; s++) {
      const int c8 = s * 4 + lhi;
      bf16x8 pa = *(const bf16x8*)&Pl[w][l16 * 64 + ((c8 ^ (l16 & 7)) << 3)];
#pragma unroll
      for (int ct2 = 0; ct2 < 4; ct2++) {
        const int d = ct2 * 16 + l16;
        bf16x8 bv = *(const bf16x8*)&Vt[d * 64 + ((c8 ^ (d & 7)) << 3)];
        acc_o[ct2] = __builtin_amdgcn_mfma_f32_16x16x32_bf16(pa, bv, acc_o[ct2], 0, 0, 0);
      }
    }
  }

  float* ob = out + base + (size_t)(m * 64 + w * 16) * D_;
#pragma unroll
  for (int ct2 = 0; ct2 < 4; ct2++) {
#pragma unroll
    for (int r = 0; r < 4; r++) {
      const int row = lhi * 4 + r, col = ct2 * 16 + l16;
      ob[(size_t)row * D_ + col] = acc_o[ct2][r] / l_run[r];
    }
  }
}

extern "C" void kernel_launch(void* const* d_in, const int* in_sizes, int n_in,
                              void* d_out, int out_size, void* d_ws, size_t ws_size,
                              hipStream_t stream) {
  const float* q = (const float*)d_in[0];
  const float* k = (const float*)d_in[1];
  const float* v = (const float*)d_in[2];
  float* out = (float*)d_out;

  // ws layout: pq (256KB) | pk (256KB) | lut (64KB) | Kswz (8MB) | Vtswz (8MB)
  float* pq = (float*)d_ws;
  float* pk = pq + (size_t)BH_ * NB_ * D_;
  int*   lut = (int*)(pk + (size_t)BH_ * NB_ * D_);
  char*  extra = (char*)(lut + (size_t)BH_ * NB_ * TOPK_);
  __bf16* kswz = (__bf16*)extra;
  __bf16* vtswz = kswz + (size_t)BH_ * NB_ * 4096;

  const size_t needed = (size_t)((char*)(vtswz + (size_t)BH_ * NB_ * 4096) - (char*)d_ws);
  const bool fast = ws_size >= needed;

  hipLaunchKernelGGL(block_means_kernel, dim3(BH_ * NB_), dim3(256), 0, stream, q, k, pq, pk);
  hipLaunchKernelGGL(blockmap_kernel, dim3(BH_ * 4), dim3(256), 0, stream, pq, pk, lut);
  if (fast) {
    hipLaunchKernelGGL(prep_kv_kernel, dim3(BH_ * NB_), dim3(256), 0, stream, k, v, kswz, vtswz);
    hipLaunchKernelGGL(sparse_attn_fast, dim3(BH_ * NB_), dim3(256), 0, stream, q, kswz, vtswz, lut, out);
  } else {
    hipLaunchKernelGGL(sparse_attn_slow, dim3(BH_ * NB_), dim3(256), 0, stream, q, k, v, lut, out);
  }
}

// Round 5
// 71.112 us; speedup vs baseline: 3.4673x; 1.0851x over previous
//
#include <hip/hip_runtime.h>
#include <hip/hip_bf16.h>

#define B_ 2
#define H_ 8
#define L_ 4096
#define D_ 64
#define NB_ 64
#define TOPK_ 16
#define BH_ 16

typedef __bf16 bf16x8 __attribute__((ext_vector_type(8)));
typedef __bf16 bf16x4 __attribute__((ext_vector_type(4)));
typedef float f32x4 __attribute__((ext_vector_type(4)));

__device__ __forceinline__ void async_copy16(void* lds, const void* g) {
  __builtin_amdgcn_global_load_lds(
      (const __attribute__((address_space(1))) void*)g,
      (__attribute__((address_space(3))) void*)lds, 16, 0, 0);
}

// ---------------------------------------------------------------------------
// Kernel 1: per-block means of q and k.  grid = BH_*NB_, 256 threads.
// ---------------------------------------------------------------------------
__global__ __launch_bounds__(256) void block_means_kernel(
    const float* __restrict__ q, const float* __restrict__ k,
    float* __restrict__ pq, float* __restrict__ pk) {
  const int blk = blockIdx.x;          // bh*64 + m
  const int bh = blk >> 6, m = blk & 63;
  const int d = threadIdx.x & 63, g = threadIdx.x >> 6;   // g in 0..3
  const float* qb = q + ((size_t)bh * L_ + m * 64 + g * 16) * D_ + d;
  const float* kb = k + ((size_t)bh * L_ + m * 64 + g * 16) * D_ + d;
  float sq = 0.f, sk = 0.f;
#pragma unroll
  for (int i = 0; i < 16; i++) { sq += qb[(size_t)i * D_]; sk += kb[(size_t)i * D_]; }
  __shared__ float bufq[4][64];
  __shared__ float bufk[4][64];
  bufq[g][d] = sq; bufk[g][d] = sk;
  __syncthreads();
  if (g == 0) {
    float tq = bufq[0][d] + bufq[1][d] + bufq[2][d] + bufq[3][d];
    float tk = bufk[0][d] + bufk[1][d] + bufk[2][d] + bufk[3][d];
    pq[(size_t)blk * 64 + d] = tq * (1.f / 64.f);
    pk[(size_t)blk * 64 + d] = tk * (1.f / 64.f);
  }
}

// ---------------------------------------------------------------------------
// Kernel 2: scores + top-16 per row by rank counting (fp32, matches np top_k
// ordering incl. lowest-index tie-break).  grid = BH_*4, 256 threads.
// ---------------------------------------------------------------------------
__global__ __launch_bounds__(256) void blockmap_kernel(
    const float* __restrict__ pq, const float* __restrict__ pk,
    int* __restrict__ lut) {
  const int g = blockIdx.x;            // bh*4 + quarter
  const int bh = g >> 2, q4 = g & 3;
  const int t = threadIdx.x;
  const int lane = t & 63, w = t >> 6;

  __shared__ float s_pk[64][65];
  __shared__ float s_km[64];
  __shared__ float s_pq[16][64];
  __shared__ float s_sc[4][64];

#pragma unroll
  for (int i = 0; i < 16; i++) {
    int idx = i * 256 + t;
    s_pk[idx >> 6][idx & 63] = pk[(size_t)bh * 4096 + idx];
  }
#pragma unroll
  for (int i = 0; i < 4; i++) {
    int idx = i * 256 + t;
    s_pq[idx >> 6][idx & 63] = pq[(size_t)bh * 4096 + q4 * 1024 + idx];
  }
  __syncthreads();
  if (t < 64) {
    float s = 0.f;
#pragma unroll 8
    for (int r = 0; r < 64; r++) s += s_pk[r][t];
    s_km[t] = s * (1.f / 64.f);
  }
  __syncthreads();

#pragma unroll
  for (int rr = 0; rr < 4; rr++) {
    const int row = w * 4 + rr;        // local row 0..15
    float sc = 0.f;
#pragma unroll 8
    for (int d2 = 0; d2 < 64; ++d2)
      sc += s_pq[row][d2] * (s_pk[lane][d2] - s_km[d2]);
    s_sc[w][lane] = sc;
    __syncthreads();
    int rank = 0;
#pragma unroll 8
    for (int j = 0; j < 64; j++) {
      float o = s_sc[w][j];
      rank += (o > sc) || (o == sc && j < lane);
    }
    if (rank < TOPK_)
      lut[((size_t)bh * 64 + q4 * 16 + row) * TOPK_ + rank] = lane;
    __syncthreads();
  }
}

// ---------------------------------------------------------------------------
// Kernel 2.5: pre-convert K -> bf16 swizzled LDS image, V -> bf16
// TRANSPOSED+swizzled LDS image, per source block (8 KB each, contiguous).
// ---------------------------------------------------------------------------
__global__ __launch_bounds__(256) void prep_kv_kernel(
    const float* __restrict__ k, const float* __restrict__ v,
    __bf16* __restrict__ kswz, __bf16* __restrict__ vtswz) {
  const int blk = blockIdx.x;
  const int tid = threadIdx.x;
  const int srow = tid >> 2;           // key row 0..63
  const int sc16 = (tid & 3) * 16;     // d col base

  const float* ks = k + (size_t)blk * 4096 + srow * 64 + sc16;
  const float* vs = v + (size_t)blk * 4096 + srow * 64 + sc16;
  float kf[16], vf[16];
#pragma unroll
  for (int h = 0; h < 4; h++) {
    float4 t4 = *(const float4*)(ks + h * 4);
    kf[h * 4 + 0] = t4.x; kf[h * 4 + 1] = t4.y; kf[h * 4 + 2] = t4.z; kf[h * 4 + 3] = t4.w;
    float4 u4 = *(const float4*)(vs + h * 4);
    vf[h * 4 + 0] = u4.x; vf[h * 4 + 1] = u4.y; vf[h * 4 + 2] = u4.z; vf[h * 4 + 3] = u4.w;
  }

  __bf16* gk = kswz + (size_t)blk * 4096;
#pragma unroll
  for (int h = 0; h < 2; h++) {
    int c8 = (sc16 >> 3) + h;
    bf16x8 kw;
#pragma unroll
    for (int j = 0; j < 8; j++) kw[j] = (__bf16)kf[h * 8 + j];
    *(bf16x8*)(gk + srow * 64 + ((c8 ^ (srow & 7)) << 3)) = kw;
  }

  __shared__ __align__(16) __bf16 s_vt[4096];
#pragma unroll
  for (int i = 0; i < 16; i++) {
    int d = sc16 + i;
    s_vt[d * 64 + (srow ^ ((d & 7) << 3))] = (__bf16)vf[i];
  }
  __syncthreads();
  __bf16* gv = vtswz + (size_t)blk * 4096;
  *(bf16x8*)(gv + tid * 8)        = *(const bf16x8*)(s_vt + tid * 8);
  *(bf16x8*)(gv + 2048 + tid * 8) = *(const bf16x8*)(s_vt + 2048 + tid * 8);
}

// ---------------------------------------------------------------------------
// Kernel 3 (fast path): sparse flash attention, SWAPPED QK^T.
// grid = BH_*NB_ (XCD-swizzled), 256 threads = 4 waves; wave w owns q rows
// [w*16, w*16+16).  accs[ct][r] = S[key=ct*16+lhi*4+r][q=l16]: each lane owns
// ONE q-row (l16) x 16 keys -> scalar m/l, local defer-max, b64 P-writes.
// Double-buffered global_load_lds staging of pre-swizzled bf16 K/V images.
// ---------------------------------------------------------------------------
__global__ __launch_bounds__(256) void sparse_attn_fast(
    const float* __restrict__ q, const __bf16* __restrict__ kswz,
    const __bf16* __restrict__ vtswz, const int* __restrict__ lut,
    float* __restrict__ out) {
  // T1: XCD-aware swizzle (1024 wgs, 8 XCDs, 128/XCD -> 2 bh per XCD-L2)
  const int bid = blockIdx.x;
  const int blk = (bid & 7) * 128 + (bid >> 3);
  const int bh = blk >> 6, m = blk & 63;
  const int tid = threadIdx.x;
  const int lane = tid & 63;
  const int w = tid >> 6;
  const int l16 = lane & 15, lhi = lane >> 4;

  __shared__ __align__(16) __bf16 KV[2][8192];   // [buf][ K:0..4095 | V:4096..8191 ]
  __shared__ __align__(16) __bf16 Pl[4][1024];

  const size_t base = (size_t)bh * L_ * D_;

  // Q B-fragments; qk_scale * log2(e) folded in (S computed in log2 domain)
  const float QSC = 0.125f * 1.44269504088896340736f;
  bf16x8 qf[2];
  {
    const float* qrow = q + base + (size_t)(m * 64 + w * 16 + l16) * D_;
#pragma unroll
    for (int s = 0; s < 2; s++) {
      const float* p0 = qrow + s * 32 + lhi * 8;
      float4 a = *(const float4*)p0;
      float4 b = *(const float4*)(p0 + 4);
      bf16x8 f;
      f[0] = (__bf16)(a.x * QSC); f[1] = (__bf16)(a.y * QSC);
      f[2] = (__bf16)(a.z * QSC); f[3] = (__bf16)(a.w * QSC);
      f[4] = (__bf16)(b.x * QSC); f[5] = (__bf16)(b.y * QSC);
      f[6] = (__bf16)(b.z * QSC); f[7] = (__bf16)(b.w * QSC);
      qf[s] = f;
    }
  }

  f32x4 acc_o[4];   // O[q=lhi*4+r][d=ct2*16+l16]
#pragma unroll
  for (int i = 0; i < 4; i++) acc_o[i] = (f32x4){0.f, 0.f, 0.f, 0.f};
  float m_run = -__builtin_inff();   // running max for q-row l16 (log2 units)
  float l_run = 0.f;                 // per-lane partial sum for q-row l16

  auto stage = [&](int b, int kb) {
    const __bf16* gk = kswz + ((size_t)(bh * 64 + kb)) * 4096;
    const __bf16* gv = vtswz + ((size_t)(bh * 64 + kb)) * 4096;
    async_copy16(&KV[b][0 * 2048 + w * 512], gk + 0 * 2048 + tid * 8);
    async_copy16(&KV[b][1 * 2048 + w * 512], gk + 1 * 2048 + tid * 8);
    async_copy16(&KV[b][4096 + 0 * 2048 + w * 512], gv + 0 * 2048 + tid * 8);
    async_copy16(&KV[b][4096 + 1 * 2048 + w * 512], gv + 1 * 2048 + tid * 8);
  };

  const size_t lutbase = (size_t)blk * TOPK_;
  stage(0, lut[lutbase]);
  __syncthreads();

  for (int it = 0; it < TOPK_; ++it) {
    const int cur = it & 1;
    if (it + 1 < TOPK_) stage(cur ^ 1, lut[lutbase + it + 1]);

    const __bf16* Kl = &KV[cur][0];
    const __bf16* Vt = &KV[cur][4096];

    // ---- S^T = K @ Q^T (log2 units): accs[ct][r] = S[ct*16+lhi*4+r][l16] ----
    f32x4 accs[4];
#pragma unroll
    for (int i = 0; i < 4; i++) accs[i] = (f32x4){0.f, 0.f, 0.f, 0.f};
    __builtin_amdgcn_s_setprio(1);
#pragma unroll
    for (int ct = 0; ct < 4; ct++) {
      const int key = ct * 16 + l16;
#pragma unroll
      for (int s = 0; s < 2; s++) {
        const int c8 = s * 4 + lhi;
        bf16x8 bk = *(const bf16x8*)&Kl[key * 64 + ((c8 ^ (key & 7)) << 3)];
        accs[ct] = __builtin_amdgcn_mfma_f32_16x16x32_bf16(bk, qf[s], accs[ct], 0, 0, 0);
      }
    }
    __builtin_amdgcn_s_setprio(0);

    // ---- online softmax: lane-local over 16 keys, defer-max (T13) ----
    float px = fmaxf(
        fmaxf(fmaxf(fmaxf(accs[0][0], accs[0][1]), fmaxf(accs[0][2], accs[0][3])),
              fmaxf(fmaxf(accs[1][0], accs[1][1]), fmaxf(accs[1][2], accs[1][3]))),
        fmaxf(fmaxf(fmaxf(accs[2][0], accs[2][1]), fmaxf(accs[2][2], accs[2][3])),
              fmaxf(fmaxf(accs[3][0], accs[3][1]), fmaxf(accs[3][2], accs[3][3]))));
    if (!__all(px <= m_run + 8.f)) {   // rare: cross-lane row max + rescale
      float mx = px;
      mx = fmaxf(mx, __shfl_xor(mx, 16, 64));
      mx = fmaxf(mx, __shfl_xor(mx, 32, 64));
      const float mnew = fmaxf(m_run, mx);
      const float sc = exp2f(m_run - mnew);
      l_run *= sc;
      m_run = mnew;
      float scq[4];
#pragma unroll
      for (int r = 0; r < 4; r++)
        scq[r] = __shfl(sc, (lane & 48) | (lhi * 4 + r), 64);
#pragma unroll
      for (int ct = 0; ct < 4; ct++)
#pragma unroll
        for (int r = 0; r < 4; r++) acc_o[ct][r] *= scq[r];
    }

    // ---- P = exp2(S - m) -> per-wave LDS (b64 writes), l partial sum ----
    float lsum = 0.f;
#pragma unroll
    for (int ct = 0; ct < 4; ct++) {
      bf16x4 pw;
#pragma unroll
      for (int r = 0; r < 4; r++) {
        float e = exp2f(accs[ct][r] - m_run);   // bounded by 2^8
        lsum += e;
        pw[r] = (__bf16)e;
      }
      const int col0 = ct * 16 + lhi * 4;       // 4-aligned; swizzle keeps run
      *(bf16x4*)&Pl[w][l16 * 64 + (col0 ^ ((l16 & 7) << 3))] = pw;
    }
    l_run += lsum;

    // ---- O += P @ V ----
    __builtin_amdgcn_s_setprio(1);
#pragma unroll
    for (int s = 0; s < 2; s++) {
      const int c8 = s * 4 + lhi;
      bf16x8 pa = *(const bf16x8*)&Pl[w][l16 * 64 + ((c8 ^ (l16 & 7)) << 3)];
#pragma unroll
      for (int ct2 = 0; ct2 < 4; ct2++) {
        const int d = ct2 * 16 + l16;
        bf16x8 bv = *(const bf16x8*)&Vt[d * 64 + ((c8 ^ (d & 7)) << 3)];
        acc_o[ct2] = __builtin_amdgcn_mfma_f32_16x16x32_bf16(pa, bv, acc_o[ct2], 0, 0, 0);
      }
    }
    __builtin_amdgcn_s_setprio(0);

    __syncthreads();   // next buffer staged; all reads of cur done
  }

  // ---- epilogue: reduce l across the 4 lanes sharing q-row, redistribute ----
  l_run += __shfl_xor(l_run, 16, 64);
  l_run += __shfl_xor(l_run, 32, 64);
  float lq[4];
#pragma unroll
  for (int r = 0; r < 4; r++)
    lq[r] = __shfl(l_run, (lane & 48) | (lhi * 4 + r), 64);

  float* ob = out + base + (size_t)(m * 64 + w * 16) * D_;
#pragma unroll
  for (int ct2 = 0; ct2 < 4; ct2++) {
#pragma unroll
    for (int r = 0; r < 4; r++) {
      const int row = lhi * 4 + r, col = ct2 * 16 + l16;
      ob[(size_t)row * D_ + col] = acc_o[ct2][r] / lq[r];
    }
  }
}

// ---------------------------------------------------------------------------
// Kernel 3 (fallback, round-2 version): only if ws_size too small.
// ---------------------------------------------------------------------------
__global__ __launch_bounds__(256) void sparse_attn_slow(
    const float* __restrict__ q, const float* __restrict__ k,
    const float* __restrict__ v, const int* __restrict__ lut,
    float* __restrict__ out) {
  const int blk = blockIdx.x;
  const int bh = blk >> 6, m = blk & 63;
  const int tid = threadIdx.x;
  const int lane = tid & 63;
  const int w = tid >> 6;
  const int l16 = lane & 15, lhi = lane >> 4;

  __shared__ __align__(16) __bf16 Kl[64 * 64];
  __shared__ __align__(16) __bf16 Vt[64 * 64];
  __shared__ __align__(16) __bf16 Pl[4][16 * 64];

  const size_t base = (size_t)bh * L_ * D_;

  bf16x8 qf[2];
  {
    const float* qrow = q + base + (size_t)(m * 64 + w * 16 + l16) * D_;
#pragma unroll
    for (int s = 0; s < 2; s++) {
      const float* p0 = qrow + s * 32 + lhi * 8;
      float4 a = *(const float4*)p0;
      float4 b = *(const float4*)(p0 + 4);
      bf16x8 f;
      f[0] = (__bf16)(a.x * 0.125f); f[1] = (__bf16)(a.y * 0.125f);
      f[2] = (__bf16)(a.z * 0.125f); f[3] = (__bf16)(a.w * 0.125f);
      f[4] = (__bf16)(b.x * 0.125f); f[5] = (__bf16)(b.y * 0.125f);
      f[6] = (__bf16)(b.z * 0.125f); f[7] = (__bf16)(b.w * 0.125f);
      qf[s] = f;
    }
  }

  f32x4 acc_o[4];
#pragma unroll
  for (int i = 0; i < 4; i++) acc_o[i] = (f32x4){0.f, 0.f, 0.f, 0.f};
  float m_run[4] = {-__builtin_inff(), -__builtin_inff(), -__builtin_inff(), -__builtin_inff()};
  float l_run[4] = {0.f, 0.f, 0.f, 0.f};

  const int srow = tid >> 2;
  const int sc16 = (tid & 3) * 16;

  for (int it = 0; it < TOPK_; ++it) {
    const int kb = lut[(size_t)blk * TOPK_ + it];
    __syncthreads();
    {
      const float* ks = k + base + (size_t)(kb * 64 + srow) * D_ + sc16;
      const float* vs = v + base + (size_t)(kb * 64 + srow) * D_ + sc16;
      float kf[16], vf[16];
#pragma unroll
      for (int h = 0; h < 4; h++) {
        float4 t4 = *(const float4*)(ks + h * 4);
        kf[h * 4 + 0] = t4.x; kf[h * 4 + 1] = t4.y; kf[h * 4 + 2] = t4.z; kf[h * 4 + 3] = t4.w;
        float4 u4 = *(const float4*)(vs + h * 4);
        vf[h * 4 + 0] = u4.x; vf[h * 4 + 1] = u4.y; vf[h * 4 + 2] = u4.z; vf[h * 4 + 3] = u4.w;
      }
#pragma unroll
      for (int h = 0; h < 2; h++) {
        int c8 = (sc16 >> 3) + h;
        bf16x8 kw;
#pragma unroll
        for (int j = 0; j < 8; j++) kw[j] = (__bf16)kf[h * 8 + j];
        *(bf16x8*)&Kl[srow * 64 + ((c8 ^ (srow & 7)) << 3)] = kw;
      }
#pragma unroll
      for (int i = 0; i < 16; i++) {
        int d = sc16 + i;
        Vt[d * 64 + (srow ^ ((d & 7) << 3))] = (__bf16)vf[i];
      }
    }
    __syncthreads();

    f32x4 accs[4];
#pragma unroll
    for (int i = 0; i < 4; i++) accs[i] = (f32x4){0.f, 0.f, 0.f, 0.f};
#pragma unroll
    for (int ct = 0; ct < 4; ct++) {
      const int key = ct * 16 + l16;
#pragma unroll
      for (int s = 0; s < 2; s++) {
        const int c8 = s * 4 + lhi;
        bf16x8 bk = *(const bf16x8*)&Kl[key * 64 + ((c8 ^ (key & 7)) << 3)];
        accs[ct] = __builtin_amdgcn_mfma_f32_16x16x32_bf16(qf[s], bk, accs[ct], 0, 0, 0);
      }
    }

    float pvals[4][4];
#pragma unroll
    for (int r = 0; r < 4; r++) {
      float mx = fmaxf(fmaxf(accs[0][r], accs[1][r]), fmaxf(accs[2][r], accs[3][r]));
#pragma unroll
      for (int off = 1; off < 16; off <<= 1) mx = fmaxf(mx, __shfl_xor(mx, off, 64));
      const float mnew = fmaxf(m_run[r], mx);
      const float scale = __expf(m_run[r] - mnew);
      float rs = 0.f;
#pragma unroll
      for (int ct = 0; ct < 4; ct++) {
        float e = __expf(accs[ct][r] - mnew);
        pvals[ct][r] = e; rs += e;
      }
#pragma unroll
      for (int off = 1; off < 16; off <<= 1) rs += __shfl_xor(rs, off, 64);
      l_run[r] = l_run[r] * scale + rs;
      m_run[r] = mnew;
#pragma unroll
      for (int ct = 0; ct < 4; ct++) acc_o[ct][r] *= scale;
    }

#pragma unroll
    for (int ct = 0; ct < 4; ct++) {
#pragma unroll
      for (int r = 0; r < 4; r++) {
        const int row = lhi * 4 + r, col = ct * 16 + l16;
        Pl[w][row * 64 + (col ^ ((row & 7) << 3))] = (__bf16)pvals[ct][r];
      }
    }
#pragma unroll
    for (int s = 0; s < 2; s++) {
      const int c8 = s * 4 + lhi;
      bf16x8 pa = *(const bf16x8*)&Pl[w][l16 * 64 + ((c8 ^ (l16 & 7)) << 3)];
#pragma unroll
      for (int ct2 = 0; ct2 < 4; ct2++) {
        const int d = ct2 * 16 + l16;
        bf16x8 bv = *(const bf16x8*)&Vt[d * 64 + ((c8 ^ (d & 7)) << 3)];
        acc_o[ct2] = __builtin_amdgcn_mfma_f32_16x16x32_bf16(pa, bv, acc_o[ct2], 0, 0, 0);
      }
    }
  }

  float* ob = out + base + (size_t)(m * 64 + w * 16) * D_;
#pragma unroll
  for (int ct2 = 0; ct2 < 4; ct2++) {
#pragma unroll
    for (int r = 0; r < 4; r++) {
      const int row = lhi * 4 + r, col = ct2 * 16 + l16;
      ob[(size_t)row * D_ + col] = acc_o[ct2][r] / l_run[r];
    }
  }
}

extern "C" void kernel_launch(void* const* d_in, const int* in_sizes, int n_in,
                              void* d_out, int out_size, void* d_ws, size_t ws_size,
                              hipStream_t stream) {
  const float* q = (const float*)d_in[0];
  const float* k = (const float*)d_in[1];
  const float* v = (const float*)d_in[2];
  float* out = (float*)d_out;

  // ws layout: pq (256KB) | pk (256KB) | lut (64KB) | Kswz (8MB) | Vtswz (8MB)
  float* pq = (float*)d_ws;
  float* pk = pq + (size_t)BH_ * NB_ * D_;
  int*   lut = (int*)(pk + (size_t)BH_ * NB_ * D_);
  char*  extra = (char*)(lut + (size_t)BH_ * NB_ * TOPK_);
  __bf16* kswz = (__bf16*)extra;
  __bf16* vtswz = kswz + (size_t)BH_ * NB_ * 4096;

  const size_t needed = (size_t)((char*)(vtswz + (size_t)BH_ * NB_ * 4096) - (char*)d_ws);
  const bool fast = ws_size >= needed;

  hipLaunchKernelGGL(block_means_kernel, dim3(BH_ * NB_), dim3(256), 0, stream, q, k, pq, pk);
  hipLaunchKernelGGL(blockmap_kernel, dim3(BH_ * 4), dim3(256), 0, stream, pq, pk, lut);
  if (fast) {
    hipLaunchKernelGGL(prep_kv_kernel, dim3(BH_ * NB_), dim3(256), 0, stream, k, v, kswz, vtswz);
    hipLaunchKernelGGL(sparse_attn_fast, dim3(BH_ * NB_), dim3(256), 0, stream, q, kswz, vtswz, lut, out);
  } else {
    hipLaunchKernelGGL(sparse_attn_slow, dim3(BH_ * NB_), dim3(256), 0, stream, q, k, v, lut, out);
  }
}

// Round 6
// 67.961 us; speedup vs baseline: 3.6281x; 1.0464x over previous
//
#include <hip/hip_runtime.h>
#include <hip/hip_bf16.h>

#define B_ 2
#define H_ 8
#define L_ 4096
#define D_ 64
#define NB_ 64
#define TOPK_ 16
#define BH_ 16

typedef __bf16 bf16x8 __attribute__((ext_vector_type(8)));
typedef __bf16 bf16x4 __attribute__((ext_vector_type(4)));
typedef float f32x4 __attribute__((ext_vector_type(4)));

__device__ __forceinline__ void async_copy16(void* lds, const void* g) {
  __builtin_amdgcn_global_load_lds(
      (const __attribute__((address_space(1))) void*)g,
      (__attribute__((address_space(3))) void*)lds, 16, 0, 0);
}

// ---------------------------------------------------------------------------
// Kernel 1: per-block means of q and k.  grid = BH_*NB_, 256 threads.
// (FROZEN: selection numerics must not change.)
// ---------------------------------------------------------------------------
__global__ __launch_bounds__(256) void block_means_kernel(
    const float* __restrict__ q, const float* __restrict__ k,
    float* __restrict__ pq, float* __restrict__ pk) {
  const int blk = blockIdx.x;          // bh*64 + m
  const int bh = blk >> 6, m = blk & 63;
  const int d = threadIdx.x & 63, g = threadIdx.x >> 6;   // g in 0..3
  const float* qb = q + ((size_t)bh * L_ + m * 64 + g * 16) * D_ + d;
  const float* kb = k + ((size_t)bh * L_ + m * 64 + g * 16) * D_ + d;
  float sq = 0.f, sk = 0.f;
#pragma unroll
  for (int i = 0; i < 16; i++) { sq += qb[(size_t)i * D_]; sk += kb[(size_t)i * D_]; }
  __shared__ float bufq[4][64];
  __shared__ float bufk[4][64];
  bufq[g][d] = sq; bufk[g][d] = sk;
  __syncthreads();
  if (g == 0) {
    float tq = bufq[0][d] + bufq[1][d] + bufq[2][d] + bufq[3][d];
    float tk = bufk[0][d] + bufk[1][d] + bufk[2][d] + bufk[3][d];
    pq[(size_t)blk * 64 + d] = tq * (1.f / 64.f);
    pk[(size_t)blk * 64 + d] = tk * (1.f / 64.f);
  }
}

// ---------------------------------------------------------------------------
// Kernel 2: scores + top-16 per row by rank counting.  (FROZEN.)
// ---------------------------------------------------------------------------
__global__ __launch_bounds__(256) void blockmap_kernel(
    const float* __restrict__ pq, const float* __restrict__ pk,
    int* __restrict__ lut) {
  const int g = blockIdx.x;            // bh*4 + quarter
  const int bh = g >> 2, q4 = g & 3;
  const int t = threadIdx.x;
  const int lane = t & 63, w = t >> 6;

  __shared__ float s_pk[64][65];
  __shared__ float s_km[64];
  __shared__ float s_pq[16][64];
  __shared__ float s_sc[4][64];

#pragma unroll
  for (int i = 0; i < 16; i++) {
    int idx = i * 256 + t;
    s_pk[idx >> 6][idx & 63] = pk[(size_t)bh * 4096 + idx];
  }
#pragma unroll
  for (int i = 0; i < 4; i++) {
    int idx = i * 256 + t;
    s_pq[idx >> 6][idx & 63] = pq[(size_t)bh * 4096 + q4 * 1024 + idx];
  }
  __syncthreads();
  if (t < 64) {
    float s = 0.f;
#pragma unroll 8
    for (int r = 0; r < 64; r++) s += s_pk[r][t];
    s_km[t] = s * (1.f / 64.f);
  }
  __syncthreads();

#pragma unroll
  for (int rr = 0; rr < 4; rr++) {
    const int row = w * 4 + rr;        // local row 0..15
    float sc = 0.f;
#pragma unroll 8
    for (int d2 = 0; d2 < 64; ++d2)
      sc += s_pq[row][d2] * (s_pk[lane][d2] - s_km[d2]);
    s_sc[w][lane] = sc;
    __syncthreads();
    int rank = 0;
#pragma unroll 8
    for (int j = 0; j < 64; j++) {
      float o = s_sc[w][j];
      rank += (o > sc) || (o == sc && j < lane);
    }
    if (rank < TOPK_)
      lut[((size_t)bh * 64 + q4 * 16 + row) * TOPK_ + rank] = lane;
    __syncthreads();
  }
}

// ---------------------------------------------------------------------------
// Kernel 2.5: pre-convert K -> bf16 swizzled image; V -> bf16 transposed,
// KEY-COLUMN-PERMUTED (kpos) + swizzled image.  The permutation makes the
// attention kernel's PV A-fragment lane-local (P never touches LDS):
//   kpos(srow) = (srow&32) + ((srow>>2)&3)*8 + ((srow>>4)&1)*4 + (srow&3)
// ---------------------------------------------------------------------------
__global__ __launch_bounds__(256) void prep_kv_kernel(
    const float* __restrict__ k, const float* __restrict__ v,
    __bf16* __restrict__ kswz, __bf16* __restrict__ vtswz) {
  const int blk = blockIdx.x;
  const int tid = threadIdx.x;
  const int srow = tid >> 2;           // key row 0..63
  const int sc16 = (tid & 3) * 16;     // d col base

  const float* ks = k + (size_t)blk * 4096 + srow * 64 + sc16;
  const float* vs = v + (size_t)blk * 4096 + srow * 64 + sc16;
  float kf[16], vf[16];
#pragma unroll
  for (int h = 0; h < 4; h++) {
    float4 t4 = *(const float4*)(ks + h * 4);
    kf[h * 4 + 0] = t4.x; kf[h * 4 + 1] = t4.y; kf[h * 4 + 2] = t4.z; kf[h * 4 + 3] = t4.w;
    float4 u4 = *(const float4*)(vs + h * 4);
    vf[h * 4 + 0] = u4.x; vf[h * 4 + 1] = u4.y; vf[h * 4 + 2] = u4.z; vf[h * 4 + 3] = u4.w;
  }

  __bf16* gk = kswz + (size_t)blk * 4096;
#pragma unroll
  for (int h = 0; h < 2; h++) {
    int c8 = (sc16 >> 3) + h;
    bf16x8 kw;
#pragma unroll
    for (int j = 0; j < 8; j++) kw[j] = (__bf16)kf[h * 8 + j];
    *(bf16x8*)(gk + srow * 64 + ((c8 ^ (srow & 7)) << 3)) = kw;
  }

  // V image: key column = kpos (PV-A-frag-local order), swizzled, via LDS.
  const int kpos = (srow & 32) + ((srow >> 2) & 3) * 8 + ((srow >> 4) & 1) * 4 + (srow & 3);
  __shared__ __align__(16) __bf16 s_vt[4096];
#pragma unroll
  for (int i = 0; i < 16; i++) {
    int d = sc16 + i;
    s_vt[d * 64 + (kpos ^ ((d & 7) << 3))] = (__bf16)vf[i];
  }
  __syncthreads();
  __bf16* gv = vtswz + (size_t)blk * 4096;
  *(bf16x8*)(gv + tid * 8)        = *(const bf16x8*)(s_vt + tid * 8);
  *(bf16x8*)(gv + 2048 + tid * 8) = *(const bf16x8*)(s_vt + 2048 + tid * 8);
}

// ---------------------------------------------------------------------------
// Kernel 3 (fast path): sparse flash attention, SWAPPED QK^T, P fully
// in-register (V-image key permutation makes accs -> PV-A-frag a pure
// in-lane repack).  grid = BH_*NB_ (XCD-swizzled), 256 threads = 4 waves.
// ---------------------------------------------------------------------------
__global__ __launch_bounds__(256) void sparse_attn_fast(
    const float* __restrict__ q, const __bf16* __restrict__ kswz,
    const __bf16* __restrict__ vtswz, const int* __restrict__ lut,
    float* __restrict__ out) {
  // T1: XCD-aware swizzle (1024 wgs, 8 XCDs -> 2 bh per XCD-L2)
  const int bid = blockIdx.x;
  const int blk = (bid & 7) * 128 + (bid >> 3);
  const int bh = blk >> 6, m = blk & 63;
  const int tid = threadIdx.x;
  const int lane = tid & 63;
  const int w = tid >> 6;
  const int l16 = lane & 15, lhi = lane >> 4;

  __shared__ __align__(16) __bf16 KV[2][8192];   // [buf][ K:0..4095 | V:4096..8191 ]

  const size_t base = (size_t)bh * L_ * D_;

  // Q B-fragments; qk_scale * log2(e) folded in (S computed in log2 domain)
  const float QSC = 0.125f * 1.44269504088896340736f;
  bf16x8 qf[2];
  {
    const float* qrow = q + base + (size_t)(m * 64 + w * 16 + l16) * D_;
#pragma unroll
    for (int s = 0; s < 2; s++) {
      const float* p0 = qrow + s * 32 + lhi * 8;
      float4 a = *(const float4*)p0;
      float4 b = *(const float4*)(p0 + 4);
      bf16x8 f;
      f[0] = (__bf16)(a.x * QSC); f[1] = (__bf16)(a.y * QSC);
      f[2] = (__bf16)(a.z * QSC); f[3] = (__bf16)(a.w * QSC);
      f[4] = (__bf16)(b.x * QSC); f[5] = (__bf16)(b.y * QSC);
      f[6] = (__bf16)(b.z * QSC); f[7] = (__bf16)(b.w * QSC);
      qf[s] = f;
    }
  }

  f32x4 acc_o[4];   // O[q=lhi*4+r][d=ct2*16+l16]
#pragma unroll
  for (int i = 0; i < 4; i++) acc_o[i] = (f32x4){0.f, 0.f, 0.f, 0.f};
  float m_run = -__builtin_inff();   // running max for q-row l16 (log2 units)
  float l_run = 0.f;                 // per-lane partial sum for q-row l16

  auto stage = [&](int b, int kb) {
    const __bf16* gk = kswz + ((size_t)(bh * 64 + kb)) * 4096;
    const __bf16* gv = vtswz + ((size_t)(bh * 64 + kb)) * 4096;
    async_copy16(&KV[b][0 * 2048 + w * 512], gk + 0 * 2048 + tid * 8);
    async_copy16(&KV[b][1 * 2048 + w * 512], gk + 1 * 2048 + tid * 8);
    async_copy16(&KV[b][4096 + 0 * 2048 + w * 512], gv + 0 * 2048 + tid * 8);
    async_copy16(&KV[b][4096 + 1 * 2048 + w * 512], gv + 1 * 2048 + tid * 8);
  };

  const size_t lutbase = (size_t)blk * TOPK_;
  stage(0, lut[lutbase]);
  __syncthreads();

  for (int it = 0; it < TOPK_; ++it) {
    const int cur = it & 1;
    if (it + 1 < TOPK_) stage(cur ^ 1, lut[lutbase + it + 1]);

    const __bf16* Kl = &KV[cur][0];
    const __bf16* Vt = &KV[cur][4096];

    // ---- S^T = K @ Q^T (log2 units): accs[ct][r] = S[img_row=16ct+4lhi+r][l16] ----
    f32x4 accs[4];
#pragma unroll
    for (int i = 0; i < 4; i++) accs[i] = (f32x4){0.f, 0.f, 0.f, 0.f};
    __builtin_amdgcn_s_setprio(1);
#pragma unroll
    for (int ct = 0; ct < 4; ct++) {
      const int key = ct * 16 + l16;
#pragma unroll
      for (int s = 0; s < 2; s++) {
        const int c8 = s * 4 + lhi;
        bf16x8 bk = *(const bf16x8*)&Kl[key * 64 + ((c8 ^ (key & 7)) << 3)];
        accs[ct] = __builtin_amdgcn_mfma_f32_16x16x32_bf16(bk, qf[s], accs[ct], 0, 0, 0);
      }
    }
    __builtin_amdgcn_s_setprio(0);

    // ---- online softmax: lane-local over 16 keys, defer-max (T13) ----
    // v_max3-friendly triples (8 ops instead of 15)
    float px = fmaxf(fmaxf(accs[0][0], accs[0][1]), accs[0][2]);
    px = fmaxf(fmaxf(px, accs[0][3]), accs[1][0]);
    px = fmaxf(fmaxf(px, accs[1][1]), accs[1][2]);
    px = fmaxf(fmaxf(px, accs[1][3]), accs[2][0]);
    px = fmaxf(fmaxf(px, accs[2][1]), accs[2][2]);
    px = fmaxf(fmaxf(px, accs[2][3]), accs[3][0]);
    px = fmaxf(fmaxf(px, accs[3][1]), accs[3][2]);
    px = fmaxf(px, accs[3][3]);
    if (!__all(px <= m_run + 8.f)) {   // rare: cross-lane row max + rescale
      float mx = px;
      mx = fmaxf(mx, __shfl_xor(mx, 16, 64));
      mx = fmaxf(mx, __shfl_xor(mx, 32, 64));
      const float mnew = fmaxf(m_run, mx);
      const float sc = exp2f(m_run - mnew);
      l_run *= sc;
      m_run = mnew;
      float scq[4];
#pragma unroll
      for (int r = 0; r < 4; r++)
        scq[r] = __shfl(sc, (lane & 48) | (lhi * 4 + r), 64);
#pragma unroll
      for (int ct = 0; ct < 4; ct++)
#pragma unroll
        for (int r = 0; r < 4; r++) acc_o[ct][r] *= scq[r];
    }

    // ---- P = exp2(S - m) straight into PV A-fragments (in-register) ----
    // pa[s2][j] = P[q=l16][kpos=32*s2+8*lhi+j] = accs[2*s2+(j>>2)][j&3]
    float lsum = 0.f;
    bf16x8 pa[2];
#pragma unroll
    for (int s2 = 0; s2 < 2; s2++) {
#pragma unroll
      for (int j = 0; j < 8; j++) {
        float e = exp2f(accs[s2 * 2 + (j >> 2)][j & 3] - m_run);  // <= 2^8
        lsum += e;
        pa[s2][j] = (__bf16)e;
      }
    }
    l_run += lsum;

    // ---- O += P @ V (V-image columns are kpos-ordered) ----
    __builtin_amdgcn_s_setprio(1);
#pragma unroll
    for (int s2 = 0; s2 < 2; s2++) {
      const int c8 = s2 * 4 + lhi;
#pragma unroll
      for (int ct2 = 0; ct2 < 4; ct2++) {
        const int d = ct2 * 16 + l16;
        bf16x8 bv = *(const bf16x8*)&Vt[d * 64 + ((c8 ^ (d & 7)) << 3)];
        acc_o[ct2] = __builtin_amdgcn_mfma_f32_16x16x32_bf16(pa[s2], bv, acc_o[ct2], 0, 0, 0);
      }
    }
    __builtin_amdgcn_s_setprio(0);

    __syncthreads();   // next buffer staged; all reads of cur done
  }

  // ---- epilogue: reduce l across the 4 lanes sharing q-row, redistribute ----
  l_run += __shfl_xor(l_run, 16, 64);
  l_run += __shfl_xor(l_run, 32, 64);
  float lq[4];
#pragma unroll
  for (int r = 0; r < 4; r++)
    lq[r] = __shfl(l_run, (lane & 48) | (lhi * 4 + r), 64);

  float* ob = out + base + (size_t)(m * 64 + w * 16) * D_;
#pragma unroll
  for (int ct2 = 0; ct2 < 4; ct2++) {
#pragma unroll
    for (int r = 0; r < 4; r++) {
      const int row = lhi * 4 + r, col = ct2 * 16 + l16;
      ob[(size_t)row * D_ + col] = acc_o[ct2][r] / lq[r];
    }
  }
}

// ---------------------------------------------------------------------------
// Kernel 3 (fallback, self-contained): only if ws_size too small.
// ---------------------------------------------------------------------------
__global__ __launch_bounds__(256) void sparse_attn_slow(
    const float* __restrict__ q, const float* __restrict__ k,
    const float* __restrict__ v, const int* __restrict__ lut,
    float* __restrict__ out) {
  const int blk = blockIdx.x;
  const int bh = blk >> 6, m = blk & 63;
  const int tid = threadIdx.x;
  const int lane = tid & 63;
  const int w = tid >> 6;
  const int l16 = lane & 15, lhi = lane >> 4;

  __shared__ __align__(16) __bf16 Kl[64 * 64];
  __shared__ __align__(16) __bf16 Vt[64 * 64];
  __shared__ __align__(16) __bf16 Pl[4][16 * 64];

  const size_t base = (size_t)bh * L_ * D_;

  bf16x8 qf[2];
  {
    const float* qrow = q + base + (size_t)(m * 64 + w * 16 + l16) * D_;
#pragma unroll
    for (int s = 0; s < 2; s++) {
      const float* p0 = qrow + s * 32 + lhi * 8;
      float4 a = *(const float4*)p0;
      float4 b = *(const float4*)(p0 + 4);
      bf16x8 f;
      f[0] = (__bf16)(a.x * 0.125f); f[1] = (__bf16)(a.y * 0.125f);
      f[2] = (__bf16)(a.z * 0.125f); f[3] = (__bf16)(a.w * 0.125f);
      f[4] = (__bf16)(b.x * 0.125f); f[5] = (__bf16)(b.y * 0.125f);
      f[6] = (__bf16)(b.z * 0.125f); f[7] = (__bf16)(b.w * 0.125f);
      qf[s] = f;
    }
  }

  f32x4 acc_o[4];
#pragma unroll
  for (int i = 0; i < 4; i++) acc_o[i] = (f32x4){0.f, 0.f, 0.f, 0.f};
  float m_run[4] = {-__builtin_inff(), -__builtin_inff(), -__builtin_inff(), -__builtin_inff()};
  float l_run[4] = {0.f, 0.f, 0.f, 0.f};

  const int srow = tid >> 2;
  const int sc16 = (tid & 3) * 16;

  for (int it = 0; it < TOPK_; ++it) {
    const int kb = lut[(size_t)blk * TOPK_ + it];
    __syncthreads();
    {
      const float* ks = k + base + (size_t)(kb * 64 + srow) * D_ + sc16;
      const float* vs = v + base + (size_t)(kb * 64 + srow) * D_ + sc16;
      float kf[16], vf[16];
#pragma unroll
      for (int h = 0; h < 4; h++) {
        float4 t4 = *(const float4*)(ks + h * 4);
        kf[h * 4 + 0] = t4.x; kf[h * 4 + 1] = t4.y; kf[h * 4 + 2] = t4.z; kf[h * 4 + 3] = t4.w;
        float4 u4 = *(const float4*)(vs + h * 4);
        vf[h * 4 + 0] = u4.x; vf[h * 4 + 1] = u4.y; vf[h * 4 + 2] = u4.z; vf[h * 4 + 3] = u4.w;
      }
#pragma unroll
      for (int h = 0; h < 2; h++) {
        int c8 = (sc16 >> 3) + h;
        bf16x8 kw;
#pragma unroll
        for (int j = 0; j < 8; j++) kw[j] = (__bf16)kf[h * 8 + j];
        *(bf16x8*)&Kl[srow * 64 + ((c8 ^ (srow & 7)) << 3)] = kw;
      }
#pragma unroll
      for (int i = 0; i < 16; i++) {
        int d = sc16 + i;
        Vt[d * 64 + (srow ^ ((d & 7) << 3))] = (__bf16)vf[i];
      }
    }
    __syncthreads();

    f32x4 accs[4];
#pragma unroll
    for (int i = 0; i < 4; i++) accs[i] = (f32x4){0.f, 0.f, 0.f, 0.f};
#pragma unroll
    for (int ct = 0; ct < 4; ct++) {
      const int key = ct * 16 + l16;
#pragma unroll
      for (int s = 0; s < 2; s++) {
        const int c8 = s * 4 + lhi;
        bf16x8 bk = *(const bf16x8*)&Kl[key * 64 + ((c8 ^ (key & 7)) << 3)];
        accs[ct] = __builtin_amdgcn_mfma_f32_16x16x32_bf16(qf[s], bk, accs[ct], 0, 0, 0);
      }
    }

    float pvals[4][4];
#pragma unroll
    for (int r = 0; r < 4; r++) {
      float mx = fmaxf(fmaxf(accs[0][r], accs[1][r]), fmaxf(accs[2][r], accs[3][r]));
#pragma unroll
      for (int off = 1; off < 16; off <<= 1) mx = fmaxf(mx, __shfl_xor(mx, off, 64));
      const float mnew = fmaxf(m_run[r], mx);
      const float scale = __expf(m_run[r] - mnew);
      float rs = 0.f;
#pragma unroll
      for (int ct = 0; ct < 4; ct++) {
        float e = __expf(accs[ct][r] - mnew);
        pvals[ct][r] = e; rs += e;
      }
#pragma unroll
      for (int off = 1; off < 16; off <<= 1) rs += __shfl_xor(rs, off, 64);
      l_run[r] = l_run[r] * scale + rs;
      m_run[r] = mnew;
#pragma unroll
      for (int ct = 0; ct < 4; ct++) acc_o[ct][r] *= scale;
    }

#pragma unroll
    for (int ct = 0; ct < 4; ct++) {
#pragma unroll
      for (int r = 0; r < 4; r++) {
        const int row = lhi * 4 + r, col = ct * 16 + l16;
        Pl[w][row * 64 + (col ^ ((row & 7) << 3))] = (__bf16)pvals[ct][r];
      }
    }
#pragma unroll
    for (int s = 0; s < 2; s++) {
      const int c8 = s * 4 + lhi;
      bf16x8 pa = *(const bf16x8*)&Pl[w][l16 * 64 + ((c8 ^ (l16 & 7)) << 3)];
#pragma unroll
      for (int ct2 = 0; ct2 < 4; ct2++) {
        const int d = ct2 * 16 + l16;
        bf16x8 bv = *(const bf16x8*)&Vt[d * 64 + ((c8 ^ (d & 7)) << 3)];
        acc_o[ct2] = __builtin_amdgcn_mfma_f32_16x16x32_bf16(pa, bv, acc_o[ct2], 0, 0, 0);
      }
    }
  }

  float* ob = out + base + (size_t)(m * 64 + w * 16) * D_;
#pragma unroll
  for (int ct2 = 0; ct2 < 4; ct2++) {
#pragma unroll
    for (int r = 0; r < 4; r++) {
      const int row = lhi * 4 + r, col = ct2 * 16 + l16;
      ob[(size_t)row * D_ + col] = acc_o[ct2][r] / l_run[r];
    }
  }
}

extern "C" void kernel_launch(void* const* d_in, const int* in_sizes, int n_in,
                              void* d_out, int out_size, void* d_ws, size_t ws_size,
                              hipStream_t stream) {
  const float* q = (const float*)d_in[0];
  const float* k = (const float*)d_in[1];
  const float* v = (const float*)d_in[2];
  float* out = (float*)d_out;

  // ws layout: pq (256KB) | pk (256KB) | lut (64KB) | Kswz (8MB) | Vtswz (8MB)
  float* pq = (float*)d_ws;
  float* pk = pq + (size_t)BH_ * NB_ * D_;
  int*   lut = (int*)(pk + (size_t)BH_ * NB_ * D_);
  char*  extra = (char*)(lut + (size_t)BH_ * NB_ * TOPK_);
  __bf16* kswz = (__bf16*)extra;
  __bf16* vtswz = kswz + (size_t)BH_ * NB_ * 4096;

  const size_t needed = (size_t)((char*)(vtswz + (size_t)BH_ * NB_ * 4096) - (char*)d_ws);
  const bool fast = ws_size >= needed;

  hipLaunchKernelGGL(block_means_kernel, dim3(BH_ * NB_), dim3(256), 0, stream, q, k, pq, pk);
  hipLaunchKernelGGL(blockmap_kernel, dim3(BH_ * 4), dim3(256), 0, stream, pq, pk, lut);
  if (fast) {
    hipLaunchKernelGGL(prep_kv_kernel, dim3(BH_ * NB_), dim3(256), 0, stream, k, v, kswz, vtswz);
    hipLaunchKernelGGL(sparse_attn_fast, dim3(BH_ * NB_), dim3(256), 0, stream, q, kswz, vtswz, lut, out);
  } else {
    hipLaunchKernelGGL(sparse_attn_slow, dim3(BH_ * NB_), dim3(256), 0, stream, q, k, v, lut, out);
  }
}